// Round 5
// baseline (239.834 us; speedup 1.0000x reference)
//
#include <hip/hip_runtime.h>
#include <math.h>

// FourierLayer: B=8, C=64, H=256, W=256, M1=M2=16.
// Pipeline (all f32):
//   A: U[bc][ky][h]   = (1/256) * sum_w x[bc][h][w] * e^{-2pi i ky w/256}        (ky 0..15)
//   B: X[bc][kxi][ky] = sum_h U[bc][ky][h] * e^{-2pi i kx h/256}, kx in {0..15,240..255}
//   Wprep: Wt[kxi][ky][i][o] = (kxi<16 ? w1 : w2)[i][o][kxi&15][ky]  (coalesced for C)
//   C: Y[b][o][kxi][ky] = sum_i X[b][i][kxi][ky] * Wt[kxi][ky][i][o]  (complex)
//   D: Z'[b][o][h][ky] = prescale * (1/256) * sum_kxi Y * e^{+2pi i kx h/256}
//      prescale: Re: ky==0 ? 1 : 2 ; Im: ky==0 ? 0 : 2   (irfft hermitian handling)
//   E: out[b][o][h][w] = sum_ky Zr'*cos(2pi ky w/256) - Zi'*sin(...) 
//                        + sum_i conv_w[o][i]*x[b][i][h][w] + conv_b[o]

#define TWOPI_256 0.024543692606170259f   // 2*pi/256
#define INV256    0.00390625f

// ---------------- workspace layout (floats) ----------------
#define NU   2097152            // 8*64*16*256
#define NX   262144             // 8*64*32*16
#define NWT  2097152            // 32*16*64*64
#define NZ   2097152            // 8*64*256*16
#define O_UR 0
#define O_UI (O_UR + NU)
#define O_XR (O_UI + NU)
#define O_XI (O_XR + NX)
#define O_WTR (O_XI + NX)
#define O_WTI (O_WTR + NWT)
#define O_YR (O_WTI + NWT)
#define O_YI (O_YR + NX)
#define O_ZR (O_YI + NX)
#define O_ZI (O_ZR + NZ)
#define O_CWT (O_ZI + NZ)       // 4096 floats
// total = 13635584 floats = ~52 MiB

// ---------------- Kernel A: forward w-transform --------------
// grid 512 (=b*64+c), block 256. Per block: all 256 h-rows, 32 output cols
// (cols 0..15 = Re ky, 16..31 = Im ky). GEMM [256 x 256] x [256 x 32].
__global__ __launch_bounds__(256) void ka_fwd_w(const float* __restrict__ x,
                                                float* __restrict__ Ur,
                                                float* __restrict__ Ui) {
    __shared__ __align__(16) float xs[32][264];   // [kk][h], transposed K-chunk
    __shared__ __align__(16) float tws[32][36];   // [kk][col]
    __shared__ float ctab[256], stab[256];
    const int tid = threadIdx.x;
    const int bc  = blockIdx.x;

    { float s, c; sincosf((float)tid * TWOPI_256, &s, &c); ctab[tid] = c; stab[tid] = s; }
    __syncthreads();

    const int rgrp = tid >> 3;        // 0..31
    const int cgrp = tid & 7;         // 0..7
    const int r0 = rgrp * 8;
    const int c0 = cgrp * 4;

    float acc[8][4];
#pragma unroll
    for (int i = 0; i < 8; ++i)
#pragma unroll
        for (int j = 0; j < 4; ++j) acc[i][j] = 0.f;

    const float* xrow = x + (size_t)bc * 65536;

    for (int k0 = 0; k0 < 256; k0 += 32) {
        // stage x chunk: xs[kk][h] = x[h][k0+kk]
#pragma unroll
        for (int it = 0; it < 8; ++it) {
            int f4 = it * 256 + tid;
            int h = f4 >> 3, j4 = f4 & 7;
            float4 v = *reinterpret_cast<const float4*>(xrow + h * 256 + k0 + j4 * 4);
            xs[j4 * 4 + 0][h] = v.x; xs[j4 * 4 + 1][h] = v.y;
            xs[j4 * 4 + 2][h] = v.z; xs[j4 * 4 + 3][h] = v.w;
        }
        // twiddle tile: col<16: +cos*inv256 (Re), col>=16: -sin*inv256 (Im)
#pragma unroll
        for (int p = 0; p < 4; ++p) {
            int idx = p * 256 + tid;
            int kk = idx >> 5, c = idx & 31;
            float v;
            if (c < 16) v =  ctab[((k0 + kk) * c) & 255] * INV256;
            else        v = -stab[((k0 + kk) * (c - 16)) & 255] * INV256;
            tws[kk][c] = v;
        }
        __syncthreads();
#pragma unroll
        for (int kk = 0; kk < 32; ++kk) {
            const float4 xv0 = *reinterpret_cast<const float4*>(&xs[kk][r0]);
            const float4 xv1 = *reinterpret_cast<const float4*>(&xs[kk][r0 + 4]);
            const float4 tw4 = *reinterpret_cast<const float4*>(&tws[kk][c0]);
            const float xv[8] = {xv0.x, xv0.y, xv0.z, xv0.w, xv1.x, xv1.y, xv1.z, xv1.w};
            const float tv[4] = {tw4.x, tw4.y, tw4.z, tw4.w};
#pragma unroll
            for (int i = 0; i < 8; ++i)
#pragma unroll
                for (int j = 0; j < 4; ++j)
                    acc[i][j] = fmaf(xv[i], tv[j], acc[i][j]);
        }
        __syncthreads();
    }

    // write U[bc][ky][h] (h-contiguous float4 pairs)
    float* Up = (c0 < 16) ? (Ur + ((size_t)bc * 16 + c0) * 256)
                          : (Ui + ((size_t)bc * 16 + (c0 - 16)) * 256);
#pragma unroll
    for (int j = 0; j < 4; ++j) {
        float4 a = {acc[0][j], acc[1][j], acc[2][j], acc[3][j]};
        float4 b = {acc[4][j], acc[5][j], acc[6][j], acc[7][j]};
        *reinterpret_cast<float4*>(Up + j * 256 + r0)     = a;
        *reinterpret_cast<float4*>(Up + j * 256 + r0 + 4) = b;
    }
}

// ---------------- Kernel B: forward h-transform --------------
// grid 512 (bc), block 256. thread: ky=t&15, kxg=t>>4 handles kxi={kxg,kxg+16}.
// Twiddle e^{-2pi i kx h/256} via in-register rotation over h.
__global__ __launch_bounds__(256) void kb_fwd_h(const float* __restrict__ Ur,
                                                const float* __restrict__ Ui,
                                                float* __restrict__ Xr,
                                                float* __restrict__ Xi) {
    __shared__ float usr[16][257], usi[16][257];
    const int tid = threadIdx.x;
    const int bc  = blockIdx.x;
    const float* urp = Ur + (size_t)bc * 4096;
    const float* uip = Ui + (size_t)bc * 4096;
#pragma unroll
    for (int it = 0; it < 4; ++it) {
        int f4 = it * 256 + tid;
        int ky = f4 >> 6, j4 = f4 & 63;
        float4 a = *reinterpret_cast<const float4*>(urp + ky * 256 + j4 * 4);
        usr[ky][j4 * 4 + 0] = a.x; usr[ky][j4 * 4 + 1] = a.y;
        usr[ky][j4 * 4 + 2] = a.z; usr[ky][j4 * 4 + 3] = a.w;
        float4 b = *reinterpret_cast<const float4*>(uip + ky * 256 + j4 * 4);
        usi[ky][j4 * 4 + 0] = b.x; usi[ky][j4 * 4 + 1] = b.y;
        usi[ky][j4 * 4 + 2] = b.z; usi[ky][j4 * 4 + 3] = b.w;
    }
    __syncthreads();

    const int ky = tid & 15, kxg = tid >> 4;
    const int kx0 = kxg, kx1 = 240 + kxg;
    float s0s, s0c, s1s, s1c;
    sincosf((float)kx0 * TWOPI_256, &s0s, &s0c);
    sincosf((float)kx1 * TWOPI_256, &s1s, &s1c);
    float t0re = 1.f, t0im = 0.f, t1re = 1.f, t1im = 0.f;  // T = e^{-i kx h theta}
    float xr0 = 0.f, xi0 = 0.f, xr1 = 0.f, xi1 = 0.f;
#pragma unroll 8
    for (int h = 0; h < 256; ++h) {
        float ur = usr[ky][h], ui = usi[ky][h];
        xr0 += ur * t0re - ui * t0im;  xi0 += ur * t0im + ui * t0re;
        xr1 += ur * t1re - ui * t1im;  xi1 += ur * t1im + ui * t1re;
        float n0re = t0re * s0c + t0im * s0s;   // T *= (c - i s)
        float n0im = t0im * s0c - t0re * s0s;
        t0re = n0re; t0im = n0im;
        float n1re = t1re * s1c + t1im * s1s;
        float n1im = t1im * s1c - t1re * s1s;
        t1re = n1re; t1im = n1im;
    }
    Xr[(size_t)bc * 512 + kxg * 16 + ky]       = xr0;
    Xi[(size_t)bc * 512 + kxg * 16 + ky]       = xi0;
    Xr[(size_t)bc * 512 + 256 + kxg * 16 + ky] = xr1;
    Xi[(size_t)bc * 512 + 256 + kxg * 16 + ky] = xi1;
}

// ---------------- Kernel Wprep: weight transpose --------------
// grid 256 = {w1r,w1i,w2r,w2i} x 64 i-planes. Wt[kxi][ky][i][o] = w[i][o][m][ky]
__global__ __launch_bounds__(256) void kw_prep(const float* __restrict__ w1r,
                                               const float* __restrict__ w1i,
                                               const float* __restrict__ w2r,
                                               const float* __restrict__ w2i,
                                               float* __restrict__ Wtr,
                                               float* __restrict__ Wti) {
    __shared__ float lds[128][65];
    const int tid = threadIdx.x;
    const int a = blockIdx.x >> 6;   // 0:w1r 1:w1i 2:w2r 3:w2i
    const int i = blockIdx.x & 63;
    const float* src = (a == 0) ? w1r : (a == 1) ? w1i : (a == 2) ? w2r : w2i;
    float* dst = (a & 1) ? Wti : Wtr;
    const int kxoff = (a >> 1) << 4;
    const float* sp = src + (size_t)i * 16384;   // w[i][o][m][ky]

    for (int p = 0; p < 2; ++p) {
        if (p) __syncthreads();
#pragma unroll
        for (int it = 0; it < 8; ++it) {
            int f4 = it * 256 + tid;             // 2048 f4 = 64 o x 32 j4
            int o = f4 >> 5, j4 = f4 & 31;
            float4 v = *reinterpret_cast<const float4*>(sp + o * 256 + p * 128 + j4 * 4);
            lds[j4 * 4 + 0][o] = v.x; lds[j4 * 4 + 1][o] = v.y;
            lds[j4 * 4 + 2][o] = v.z; lds[j4 * 4 + 3][o] = v.w;
        }
        __syncthreads();
        const int o = tid & 63, mq = tid >> 6;
#pragma unroll
        for (int r = 0; r < 32; ++r) {
            int lm = r * 4 + mq;                 // 0..127
            int mky = p * 128 + lm;
            int m = mky >> 4, ky = mky & 15;
            dst[((((size_t)(kxoff + m)) * 16 + ky) * 64 + i) * 64 + o] = lds[lm][o];
        }
    }
}

// conv_w transpose: cwT[i][o] = conv_w[o][i]
__global__ __launch_bounds__(256) void kcw_prep(const float* __restrict__ cw,
                                                float* __restrict__ cwT) {
    int idx = blockIdx.x * 256 + threadIdx.x;    // 4096
    int i = idx >> 6, o = idx & 63;
    cwT[i * 64 + o] = cw[o * 64 + i];
}

// ---------------- Kernel C: channel mixing --------------
// grid 512 (mode = kxi*16+ky), block 256. thread: o=t&63, b in {t>>6, t>>6+4}.
__global__ __launch_bounds__(256) void kc_mix(const float* __restrict__ Xr,
                                              const float* __restrict__ Xi,
                                              const float* __restrict__ Wtr,
                                              const float* __restrict__ Wti,
                                              float* __restrict__ Yr,
                                              float* __restrict__ Yi) {
    __shared__ float xsr[512], xsi[512];
    const int tid = threadIdx.x;
    const int mode = blockIdx.x;
#pragma unroll
    for (int r = 0; r < 2; ++r) {
        int bi = r * 256 + tid;                  // b*64+i
        xsr[bi] = Xr[(size_t)bi * 512 + mode];
        xsi[bi] = Xi[(size_t)bi * 512 + mode];
    }
    __syncthreads();
    const int o = tid & 63, bg = tid >> 6;
    float yr0 = 0.f, yi0 = 0.f, yr1 = 0.f, yi1 = 0.f;
    const float* wrp = Wtr + (size_t)mode * 4096;
    const float* wip = Wti + (size_t)mode * 4096;
#pragma unroll 8
    for (int i = 0; i < 64; ++i) {
        float wr = wrp[i * 64 + o], wi = wip[i * 64 + o];
        float xr = xsr[bg * 64 + i],        xi = xsi[bg * 64 + i];
        yr0 += xr * wr - xi * wi;  yi0 += xr * wi + xi * wr;
        float xr2 = xsr[(bg + 4) * 64 + i], xi2 = xsi[(bg + 4) * 64 + i];
        yr1 += xr2 * wr - xi2 * wi;  yi1 += xr2 * wi + xi2 * wr;
    }
    Yr[((size_t)bg * 64 + o) * 512 + mode]       = yr0;
    Yi[((size_t)bg * 64 + o) * 512 + mode]       = yi0;
    Yr[((size_t)(bg + 4) * 64 + o) * 512 + mode] = yr1;
    Yi[((size_t)(bg + 4) * 64 + o) * 512 + mode] = yi1;
}

// ---------------- Kernel D: inverse h-transform --------------
// grid 512 (bo), block 256 (thread = h). Rotation over kxi (step e^{+2pi i h/256}).
__global__ __launch_bounds__(256) void kd_inv_h(const float* __restrict__ Yr,
                                                const float* __restrict__ Yi,
                                                float* __restrict__ Zr,
                                                float* __restrict__ Zi) {
    __shared__ __align__(16) float2 ysz[512];
    const int tid = threadIdx.x;
    const int bo = blockIdx.x;
#pragma unroll
    for (int r = 0; r < 2; ++r) {
        int m = r * 256 + tid;
        ysz[m] = make_float2(Yr[(size_t)bo * 512 + m], Yi[(size_t)bo * 512 + m]);
    }
    __syncthreads();
    const int h = tid;
    float stepS, stepC;
    sincosf((float)h * TWOPI_256, &stepS, &stepC);   // e^{+2pi i h/256}
    float accR[16], accI[16];
#pragma unroll
    for (int k = 0; k < 16; ++k) { accR[k] = 0.f; accI[k] = 0.f; }
    float tre = 1.f, tim = 0.f;
    for (int kxi = 0; kxi < 32; ++kxi) {
        if (kxi == 16) {
            int m0 = (240 * h) & 255;                // kx=240 re-init
            sincosf((float)m0 * TWOPI_256, &tim, &tre);
        }
        const float4* yp = reinterpret_cast<const float4*>(&ysz[kxi * 16]);
#pragma unroll
        for (int k2 = 0; k2 < 8; ++k2) {
            float4 y = yp[k2];                       // (yr0,yi0,yr1,yi1)
            accR[2 * k2]     += y.x * tre - y.y * tim;
            accI[2 * k2]     += y.x * tim + y.y * tre;
            accR[2 * k2 + 1] += y.z * tre - y.w * tim;
            accI[2 * k2 + 1] += y.z * tim + y.w * tre;
        }
        float nre = tre * stepC - tim * stepS;       // T *= e^{+i h theta}
        float nim = tre * stepS + tim * stepC;
        tre = nre; tim = nim;
    }
    const float s1 = INV256, s2 = 2.f * INV256;      // irfft prescale + ortho norm
    float* zrp = Zr + ((size_t)bo * 256 + h) * 16;
    float* zip = Zi + ((size_t)bo * 256 + h) * 16;
    float4 r0 = {accR[0] * s1,  accR[1] * s2,  accR[2] * s2,  accR[3] * s2};
    float4 r1 = {accR[4] * s2,  accR[5] * s2,  accR[6] * s2,  accR[7] * s2};
    float4 r2 = {accR[8] * s2,  accR[9] * s2,  accR[10] * s2, accR[11] * s2};
    float4 r3 = {accR[12] * s2, accR[13] * s2, accR[14] * s2, accR[15] * s2};
    float4 i0 = {0.f,           accI[1] * s2,  accI[2] * s2,  accI[3] * s2};
    float4 i1 = {accI[4] * s2,  accI[5] * s2,  accI[6] * s2,  accI[7] * s2};
    float4 i2 = {accI[8] * s2,  accI[9] * s2,  accI[10] * s2, accI[11] * s2};
    float4 i3 = {accI[12] * s2, accI[13] * s2, accI[14] * s2, accI[15] * s2};
    reinterpret_cast<float4*>(zrp)[0] = r0; reinterpret_cast<float4*>(zrp)[1] = r1;
    reinterpret_cast<float4*>(zrp)[2] = r2; reinterpret_cast<float4*>(zrp)[3] = r3;
    reinterpret_cast<float4*>(zip)[0] = i0; reinterpret_cast<float4*>(zip)[1] = i1;
    reinterpret_cast<float4*>(zip)[2] = i2; reinterpret_cast<float4*>(zip)[3] = i3;
}

// ---------------- Kernel E: spectral reconstruction + conv + bias ----------
// grid 4096 = (b, h, w-half). block 256: thread tile 8o x 4w over 64o x 128w.
__global__ __launch_bounds__(256) void ke_final(const float* __restrict__ x,
                                                const float* __restrict__ Zr,
                                                const float* __restrict__ Zi,
                                                const float* __restrict__ cwT,
                                                const float* __restrict__ bias,
                                                float* __restrict__ out) {
    __shared__ __align__(16) float xsh[64][136];
    __shared__ __align__(16) float zsr[16][68], zsi[16][68];
    __shared__ __align__(16) float cosT[16][136], sinT[16][136];
    const int tid = threadIdx.x;
    const int blk = blockIdx.x;
    const int b = blk >> 9;
    const int h = (blk >> 1) & 255;
    const int wh = blk & 1;
    const int wbase = wh * 128;

    const float* xp = x + ((size_t)b * 64 * 256 + h) * 256 + wbase;
#pragma unroll
    for (int it = 0; it < 8; ++it) {
        int f4 = it * 256 + tid;                 // 2048 f4 = 64 i x 32
        int i = f4 >> 5, j4 = f4 & 31;
        float4 v = *reinterpret_cast<const float4*>(xp + (size_t)i * 65536 + j4 * 4);
        *reinterpret_cast<float4*>(&xsh[i][j4 * 4]) = v;
    }
#pragma unroll
    for (int r = 0; r < 4; ++r) {
        int idx = r * 256 + tid;                 // 1024 = 64 o x 16 ky
        int o = idx >> 4, ky = idx & 15;
        size_t zoff = (((size_t)b * 64 + o) * 256 + h) * 16 + ky;
        zsr[ky][o] = Zr[zoff];
        zsi[ky][o] = Zi[zoff];
    }
#pragma unroll
    for (int r = 0; r < 8; ++r) {
        int idx = r * 256 + tid;                 // 2048 = 16 ky x 128 w
        int ky = idx >> 7, w = idx & 127;
        int m = (ky * (wbase + w)) & 255;
        float s, c;
        sincosf((float)m * TWOPI_256, &s, &c);
        cosT[ky][w] = c; sinT[ky][w] = s;
    }
    __syncthreads();

    const int og = tid >> 5, wg = tid & 31;
    const int o0 = og * 8, w0 = wg * 4;
    float acc[8][4];
#pragma unroll
    for (int i = 0; i < 8; ++i) {
        float bv = bias[o0 + i];
        acc[i][0] = bv; acc[i][1] = bv; acc[i][2] = bv; acc[i][3] = bv;
    }
    // spectral: sum_ky Zr'*cos - Zi'*sin
#pragma unroll
    for (int ky = 0; ky < 16; ++ky) {
        const float4 cv4 = *reinterpret_cast<const float4*>(&cosT[ky][w0]);
        const float4 sv4 = *reinterpret_cast<const float4*>(&sinT[ky][w0]);
        const float4 a0 = *reinterpret_cast<const float4*>(&zsr[ky][o0]);
        const float4 a1 = *reinterpret_cast<const float4*>(&zsr[ky][o0 + 4]);
        const float4 b0 = *reinterpret_cast<const float4*>(&zsi[ky][o0]);
        const float4 b1 = *reinterpret_cast<const float4*>(&zsi[ky][o0 + 4]);
        const float zr[8] = {a0.x, a0.y, a0.z, a0.w, a1.x, a1.y, a1.z, a1.w};
        const float zi[8] = {b0.x, b0.y, b0.z, b0.w, b1.x, b1.y, b1.z, b1.w};
        const float cv[4] = {cv4.x, cv4.y, cv4.z, cv4.w};
        const float sv[4] = {sv4.x, sv4.y, sv4.z, sv4.w};
#pragma unroll
        for (int i = 0; i < 8; ++i)
#pragma unroll
            for (int j = 0; j < 4; ++j)
                acc[i][j] += zr[i] * cv[j] - zi[i] * sv[j];
    }
    // conv: sum_ci cw[o][ci] * x[ci][w]
#pragma unroll 8
    for (int ci = 0; ci < 64; ++ci) {
        const float4 xv4 = *reinterpret_cast<const float4*>(&xsh[ci][w0]);
        const float4 c0 = *reinterpret_cast<const float4*>(cwT + ci * 64 + o0);
        const float4 c1 = *reinterpret_cast<const float4*>(cwT + ci * 64 + o0 + 4);
        const float xv[4] = {xv4.x, xv4.y, xv4.z, xv4.w};
        const float cc[8] = {c0.x, c0.y, c0.z, c0.w, c1.x, c1.y, c1.z, c1.w};
#pragma unroll
        for (int i = 0; i < 8; ++i)
#pragma unroll
            for (int j = 0; j < 4; ++j)
                acc[i][j] = fmaf(cc[i], xv[j], acc[i][j]);
    }
#pragma unroll
    for (int i = 0; i < 8; ++i) {
        float4 v = {acc[i][0], acc[i][1], acc[i][2], acc[i][3]};
        *reinterpret_cast<float4*>(out + (((size_t)b * 64 + o0 + i) * 256 + h) * 256
                                   + wbase + w0) = v;
    }
}

extern "C" void kernel_launch(void* const* d_in, const int* in_sizes, int n_in,
                              void* d_out, int out_size, void* d_ws, size_t ws_size,
                              hipStream_t stream) {
    const float* x   = (const float*)d_in[0];
    const float* w1r = (const float*)d_in[1];
    const float* w1i = (const float*)d_in[2];
    const float* w2r = (const float*)d_in[3];
    const float* w2i = (const float*)d_in[4];
    const float* cw  = (const float*)d_in[5];
    const float* cb  = (const float*)d_in[6];
    float* out = (float*)d_out;
    float* ws  = (float*)d_ws;

    ka_fwd_w<<<512, 256, 0, stream>>>(x, ws + O_UR, ws + O_UI);
    kb_fwd_h<<<512, 256, 0, stream>>>(ws + O_UR, ws + O_UI, ws + O_XR, ws + O_XI);
    kw_prep<<<256, 256, 0, stream>>>(w1r, w1i, w2r, w2i, ws + O_WTR, ws + O_WTI);
    kcw_prep<<<16, 256, 0, stream>>>(cw, ws + O_CWT);
    kc_mix<<<512, 256, 0, stream>>>(ws + O_XR, ws + O_XI, ws + O_WTR, ws + O_WTI,
                                    ws + O_YR, ws + O_YI);
    kd_inv_h<<<512, 256, 0, stream>>>(ws + O_YR, ws + O_YI, ws + O_ZR, ws + O_ZI);
    ke_final<<<4096, 256, 0, stream>>>(x, ws + O_ZR, ws + O_ZI, ws + O_CWT, cb, out);
}

// Round 6
// 182.768 us; speedup vs baseline: 1.3122x; 1.3122x over previous
//
#include <hip/hip_runtime.h>
#include <math.h>

// FourierLayer: B=8, C=64, H=256, W=256, M1=M2=16.
// Pipeline (A..D f32 VALU, E bf16 MFMA):
//   A: U[bc][ky][h]   = (1/256) * sum_w x[bc][h][w] * e^{-2pi i ky w/256}        (ky 0..15)
//   B: X[bc][kxi][ky] = sum_h U[bc][ky][h] * e^{-2pi i kx h/256}, kx in {0..15,240..255}
//   Wprep: Wt[kxi][ky][i][o] = (kxi<16 ? w1 : w2)[i][o][kxi&15][ky]
//   C: Y[b][o][kxi][ky] = sum_i X[b][i][kxi][ky] * Wt[kxi][ky][i][o]  (complex)
//   D: Z'[b][o][h][ky] = prescale * (1/256) * sum_kxi Y * e^{+2pi i kx h/256}
//   E (MFMA): out[64o][256w] = [cw | Z'] (64x96 bf16) @ [x ; trig] (96x256 bf16) + bias
//      per (b,h) block; k 0..63 = conv channels, k 64..95 = (Zr,Zi) x (cos,-sin)

#define TWOPI_256 0.024543692606170259f   // 2*pi/256
#define INV256    0.00390625f

// ---------------- workspace layout (floats) ----------------
#define NU   2097152            // 8*64*16*256
#define NX   262144             // 8*64*32*16
#define NWT  2097152            // 32*16*64*64
#define NZ   2097152            // 8*64*256*16
#define O_UR 0
#define O_UI (O_UR + NU)
#define O_XR (O_UI + NU)
#define O_XI (O_XR + NX)
#define O_WTR (O_XI + NX)
#define O_WTI (O_WTR + NWT)
#define O_YR (O_WTI + NWT)
#define O_YI (O_YR + NX)
#define O_ZR (O_YI + NX)
#define O_ZI (O_ZR + NZ)
#define O_TT (O_ZI + NZ)        // trig table: 8192 ushort = 16 KB (4096 float slots)

using s16x8 = __attribute__((ext_vector_type(8))) short;   // 8 bf16 (4 VGPRs)
using f32x4 = __attribute__((ext_vector_type(4))) float;   // MFMA acc

__device__ __forceinline__ unsigned short f2bf(float f) {  // RNE f32->bf16
    union { float f; unsigned u; } a; a.f = f;
    unsigned r = (a.u + 0x7fffu + ((a.u >> 16) & 1u)) >> 16;
    return (unsigned short)r;
}

// ---------------- Kernel A: forward w-transform --------------
__global__ __launch_bounds__(256) void ka_fwd_w(const float* __restrict__ x,
                                                float* __restrict__ Ur,
                                                float* __restrict__ Ui) {
    __shared__ __align__(16) float xs[32][264];
    __shared__ __align__(16) float tws[32][36];
    __shared__ float ctab[256], stab[256];
    const int tid = threadIdx.x;
    const int bc  = blockIdx.x;

    { float s, c; sincosf((float)tid * TWOPI_256, &s, &c); ctab[tid] = c; stab[tid] = s; }
    __syncthreads();

    const int rgrp = tid >> 3;
    const int cgrp = tid & 7;
    const int r0 = rgrp * 8;
    const int c0 = cgrp * 4;

    float acc[8][4];
#pragma unroll
    for (int i = 0; i < 8; ++i)
#pragma unroll
        for (int j = 0; j < 4; ++j) acc[i][j] = 0.f;

    const float* xrow = x + (size_t)bc * 65536;

    for (int k0 = 0; k0 < 256; k0 += 32) {
#pragma unroll
        for (int it = 0; it < 8; ++it) {
            int f4 = it * 256 + tid;
            int h = f4 >> 3, j4 = f4 & 7;
            float4 v = *reinterpret_cast<const float4*>(xrow + h * 256 + k0 + j4 * 4);
            xs[j4 * 4 + 0][h] = v.x; xs[j4 * 4 + 1][h] = v.y;
            xs[j4 * 4 + 2][h] = v.z; xs[j4 * 4 + 3][h] = v.w;
        }
#pragma unroll
        for (int p = 0; p < 4; ++p) {
            int idx = p * 256 + tid;
            int kk = idx >> 5, c = idx & 31;
            float v;
            if (c < 16) v =  ctab[((k0 + kk) * c) & 255] * INV256;
            else        v = -stab[((k0 + kk) * (c - 16)) & 255] * INV256;
            tws[kk][c] = v;
        }
        __syncthreads();
#pragma unroll
        for (int kk = 0; kk < 32; ++kk) {
            const float4 xv0 = *reinterpret_cast<const float4*>(&xs[kk][r0]);
            const float4 xv1 = *reinterpret_cast<const float4*>(&xs[kk][r0 + 4]);
            const float4 tw4 = *reinterpret_cast<const float4*>(&tws[kk][c0]);
            const float xv[8] = {xv0.x, xv0.y, xv0.z, xv0.w, xv1.x, xv1.y, xv1.z, xv1.w};
            const float tv[4] = {tw4.x, tw4.y, tw4.z, tw4.w};
#pragma unroll
            for (int i = 0; i < 8; ++i)
#pragma unroll
                for (int j = 0; j < 4; ++j)
                    acc[i][j] = fmaf(xv[i], tv[j], acc[i][j]);
        }
        __syncthreads();
    }

    float* Up = (c0 < 16) ? (Ur + ((size_t)bc * 16 + c0) * 256)
                          : (Ui + ((size_t)bc * 16 + (c0 - 16)) * 256);
#pragma unroll
    for (int j = 0; j < 4; ++j) {
        float4 a = {acc[0][j], acc[1][j], acc[2][j], acc[3][j]};
        float4 b = {acc[4][j], acc[5][j], acc[6][j], acc[7][j]};
        *reinterpret_cast<float4*>(Up + j * 256 + r0)     = a;
        *reinterpret_cast<float4*>(Up + j * 256 + r0 + 4) = b;
    }
}

// ---------------- Kernel B: forward h-transform --------------
__global__ __launch_bounds__(256) void kb_fwd_h(const float* __restrict__ Ur,
                                                const float* __restrict__ Ui,
                                                float* __restrict__ Xr,
                                                float* __restrict__ Xi) {
    __shared__ float usr[16][257], usi[16][257];
    const int tid = threadIdx.x;
    const int bc  = blockIdx.x;
    const float* urp = Ur + (size_t)bc * 4096;
    const float* uip = Ui + (size_t)bc * 4096;
#pragma unroll
    for (int it = 0; it < 4; ++it) {
        int f4 = it * 256 + tid;
        int ky = f4 >> 6, j4 = f4 & 63;
        float4 a = *reinterpret_cast<const float4*>(urp + ky * 256 + j4 * 4);
        usr[ky][j4 * 4 + 0] = a.x; usr[ky][j4 * 4 + 1] = a.y;
        usr[ky][j4 * 4 + 2] = a.z; usr[ky][j4 * 4 + 3] = a.w;
        float4 b = *reinterpret_cast<const float4*>(uip + ky * 256 + j4 * 4);
        usi[ky][j4 * 4 + 0] = b.x; usi[ky][j4 * 4 + 1] = b.y;
        usi[ky][j4 * 4 + 2] = b.z; usi[ky][j4 * 4 + 3] = b.w;
    }
    __syncthreads();

    const int ky = tid & 15, kxg = tid >> 4;
    const int kx0 = kxg, kx1 = 240 + kxg;
    float s0s, s0c, s1s, s1c;
    sincosf((float)kx0 * TWOPI_256, &s0s, &s0c);
    sincosf((float)kx1 * TWOPI_256, &s1s, &s1c);
    float t0re = 1.f, t0im = 0.f, t1re = 1.f, t1im = 0.f;
    float xr0 = 0.f, xi0 = 0.f, xr1 = 0.f, xi1 = 0.f;
#pragma unroll 8
    for (int h = 0; h < 256; ++h) {
        float ur = usr[ky][h], ui = usi[ky][h];
        xr0 += ur * t0re - ui * t0im;  xi0 += ur * t0im + ui * t0re;
        xr1 += ur * t1re - ui * t1im;  xi1 += ur * t1im + ui * t1re;
        float n0re = t0re * s0c + t0im * s0s;
        float n0im = t0im * s0c - t0re * s0s;
        t0re = n0re; t0im = n0im;
        float n1re = t1re * s1c + t1im * s1s;
        float n1im = t1im * s1c - t1re * s1s;
        t1re = n1re; t1im = n1im;
    }
    Xr[(size_t)bc * 512 + kxg * 16 + ky]       = xr0;
    Xi[(size_t)bc * 512 + kxg * 16 + ky]       = xi0;
    Xr[(size_t)bc * 512 + 256 + kxg * 16 + ky] = xr1;
    Xi[(size_t)bc * 512 + 256 + kxg * 16 + ky] = xi1;
}

// ---------------- Kernel Wprep: weight transpose --------------
__global__ __launch_bounds__(256) void kw_prep(const float* __restrict__ w1r,
                                               const float* __restrict__ w1i,
                                               const float* __restrict__ w2r,
                                               const float* __restrict__ w2i,
                                               float* __restrict__ Wtr,
                                               float* __restrict__ Wti) {
    __shared__ float lds[128][65];
    const int tid = threadIdx.x;
    const int a = blockIdx.x >> 6;
    const int i = blockIdx.x & 63;
    const float* src = (a == 0) ? w1r : (a == 1) ? w1i : (a == 2) ? w2r : w2i;
    float* dst = (a & 1) ? Wti : Wtr;
    const int kxoff = (a >> 1) << 4;
    const float* sp = src + (size_t)i * 16384;

    for (int p = 0; p < 2; ++p) {
        if (p) __syncthreads();
#pragma unroll
        for (int it = 0; it < 8; ++it) {
            int f4 = it * 256 + tid;
            int o = f4 >> 5, j4 = f4 & 31;
            float4 v = *reinterpret_cast<const float4*>(sp + o * 256 + p * 128 + j4 * 4);
            lds[j4 * 4 + 0][o] = v.x; lds[j4 * 4 + 1][o] = v.y;
            lds[j4 * 4 + 2][o] = v.z; lds[j4 * 4 + 3][o] = v.w;
        }
        __syncthreads();
        const int o = tid & 63, mq = tid >> 6;
#pragma unroll
        for (int r = 0; r < 32; ++r) {
            int lm = r * 4 + mq;
            int mky = p * 128 + lm;
            int mm = mky >> 4, ky = mky & 15;
            dst[((((size_t)(kxoff + mm)) * 16 + ky) * 64 + i) * 64 + o] = lds[lm][o];
        }
    }
}

// trig table: ttab[w][kk] bf16, kk=2*ky+c: c==0 -> cos(2pi ky w/256), c==1 -> -sin
__global__ __launch_bounds__(256) void ktrig(unsigned short* __restrict__ ttab) {
    int idx = blockIdx.x * 256 + threadIdx.x;    // 8192 = 256 w x 32 kk
    int w = idx >> 5, kk = idx & 31, ky = kk >> 1;
    int mm = (ky * w) & 255;
    float s, c;
    sincosf((float)mm * TWOPI_256, &s, &c);
    ttab[idx] = f2bf((kk & 1) ? -s : c);
}

// ---------------- Kernel C: channel mixing --------------
__global__ __launch_bounds__(256) void kc_mix(const float* __restrict__ Xr,
                                              const float* __restrict__ Xi,
                                              const float* __restrict__ Wtr,
                                              const float* __restrict__ Wti,
                                              float* __restrict__ Yr,
                                              float* __restrict__ Yi) {
    __shared__ float xsr[512], xsi[512];
    const int tid = threadIdx.x;
    const int mode = blockIdx.x;
#pragma unroll
    for (int r = 0; r < 2; ++r) {
        int bi = r * 256 + tid;
        xsr[bi] = Xr[(size_t)bi * 512 + mode];
        xsi[bi] = Xi[(size_t)bi * 512 + mode];
    }
    __syncthreads();
    const int o = tid & 63, bg = tid >> 6;
    float yr0 = 0.f, yi0 = 0.f, yr1 = 0.f, yi1 = 0.f;
    const float* wrp = Wtr + (size_t)mode * 4096;
    const float* wip = Wti + (size_t)mode * 4096;
#pragma unroll 8
    for (int i = 0; i < 64; ++i) {
        float wr = wrp[i * 64 + o], wi = wip[i * 64 + o];
        float xr = xsr[bg * 64 + i],        xi = xsi[bg * 64 + i];
        yr0 += xr * wr - xi * wi;  yi0 += xr * wi + xi * wr;
        float xr2 = xsr[(bg + 4) * 64 + i], xi2 = xsi[(bg + 4) * 64 + i];
        yr1 += xr2 * wr - xi2 * wi;  yi1 += xr2 * wi + xi2 * wr;
    }
    Yr[((size_t)bg * 64 + o) * 512 + mode]       = yr0;
    Yi[((size_t)bg * 64 + o) * 512 + mode]       = yi0;
    Yr[((size_t)(bg + 4) * 64 + o) * 512 + mode] = yr1;
    Yi[((size_t)(bg + 4) * 64 + o) * 512 + mode] = yi1;
}

// ---------------- Kernel D: inverse h-transform --------------
__global__ __launch_bounds__(256) void kd_inv_h(const float* __restrict__ Yr,
                                                const float* __restrict__ Yi,
                                                float* __restrict__ Zr,
                                                float* __restrict__ Zi) {
    __shared__ __align__(16) float2 ysz[512];
    const int tid = threadIdx.x;
    const int bo = blockIdx.x;
#pragma unroll
    for (int r = 0; r < 2; ++r) {
        int mm = r * 256 + tid;
        ysz[mm] = make_float2(Yr[(size_t)bo * 512 + mm], Yi[(size_t)bo * 512 + mm]);
    }
    __syncthreads();
    const int h = tid;
    float stepS, stepC;
    sincosf((float)h * TWOPI_256, &stepS, &stepC);
    float accR[16], accI[16];
#pragma unroll
    for (int k = 0; k < 16; ++k) { accR[k] = 0.f; accI[k] = 0.f; }
    float tre = 1.f, tim = 0.f;
    for (int kxi = 0; kxi < 32; ++kxi) {
        if (kxi == 16) {
            int m0 = (240 * h) & 255;
            sincosf((float)m0 * TWOPI_256, &tim, &tre);
        }
        const float4* yp = reinterpret_cast<const float4*>(&ysz[kxi * 16]);
#pragma unroll
        for (int k2 = 0; k2 < 8; ++k2) {
            float4 y = yp[k2];
            accR[2 * k2]     += y.x * tre - y.y * tim;
            accI[2 * k2]     += y.x * tim + y.y * tre;
            accR[2 * k2 + 1] += y.z * tre - y.w * tim;
            accI[2 * k2 + 1] += y.z * tim + y.w * tre;
        }
        float nre = tre * stepC - tim * stepS;
        float nim = tre * stepS + tim * stepC;
        tre = nre; tim = nim;
    }
    const float s1 = INV256, s2 = 2.f * INV256;
    float* zrp = Zr + ((size_t)bo * 256 + h) * 16;
    float* zip = Zi + ((size_t)bo * 256 + h) * 16;
    float4 r0 = {accR[0] * s1,  accR[1] * s2,  accR[2] * s2,  accR[3] * s2};
    float4 r1 = {accR[4] * s2,  accR[5] * s2,  accR[6] * s2,  accR[7] * s2};
    float4 r2 = {accR[8] * s2,  accR[9] * s2,  accR[10] * s2, accR[11] * s2};
    float4 r3 = {accR[12] * s2, accR[13] * s2, accR[14] * s2, accR[15] * s2};
    float4 i0 = {0.f,           accI[1] * s2,  accI[2] * s2,  accI[3] * s2};
    float4 i1 = {accI[4] * s2,  accI[5] * s2,  accI[6] * s2,  accI[7] * s2};
    float4 i2 = {accI[8] * s2,  accI[9] * s2,  accI[10] * s2, accI[11] * s2};
    float4 i3 = {accI[12] * s2, accI[13] * s2, accI[14] * s2, accI[15] * s2};
    reinterpret_cast<float4*>(zrp)[0] = r0; reinterpret_cast<float4*>(zrp)[1] = r1;
    reinterpret_cast<float4*>(zrp)[2] = r2; reinterpret_cast<float4*>(zrp)[3] = r3;
    reinterpret_cast<float4*>(zip)[0] = i0; reinterpret_cast<float4*>(zip)[1] = i1;
    reinterpret_cast<float4*>(zip)[2] = i2; reinterpret_cast<float4*>(zip)[3] = i3;
}

// ---------------- Kernel E (MFMA): out = [cw|Z'] @ [x;trig] + bias ----------
// Grid 2048 = (b,h). Block 512 = 8 waves (2 o-groups x ... o-split 4, w-split 2).
// Wave tile: 16 o x 128 w = 8 MFMA frags, K = 96 (3 k-steps of 32).
// LDS: x as bf16 pairs [w][i-pair], 16B blocks XOR-swizzled by c(w)=(w^(w>>3))&7.
__global__ __launch_bounds__(512) void ke_mfma(const float* __restrict__ x,
                                               const float* __restrict__ Zr,
                                               const float* __restrict__ Zi,
                                               const float* __restrict__ cw,
                                               const float* __restrict__ bias,
                                               const unsigned short* __restrict__ ttab,
                                               float* __restrict__ out) {
    __shared__ unsigned int bsx[8192];   // 32 KB: [w=256][16 words], swizzled
    const int tid = threadIdx.x;
    const int b = blockIdx.x >> 8;
    const int h = blockIdx.x & 255;

    // ---- staging loads: x[b][2ip(+1)][h][w0..w0+3] ----
    const size_t xbase = ((size_t)b * 64) * 65536 + (size_t)h * 256;
    const int w0s = (tid & 63) * 4;
    float4 va[4], vb[4];
#pragma unroll
    for (int it = 0; it < 4; ++it) {
        int ip = it * 8 + (tid >> 6);
        va[it] = *reinterpret_cast<const float4*>(x + xbase + (size_t)(2 * ip) * 65536 + w0s);
        vb[it] = *reinterpret_cast<const float4*>(x + xbase + (size_t)(2 * ip + 1) * 65536 + w0s);
    }

    const int m = tid & 15;            // lane row index (A-row o / B-row w)
    const int g = (tid >> 4) & 3;      // k-group
    const int wave = tid >> 6;
    const int o0 = (wave >> 1) * 16;
    const int f0 = (wave & 1) * 8;
    const int o = o0 + m;

    // ---- preload register fragments (L2-hot globals) ----
    s16x8 a0, a1, az;
    {
        f32x4 p  = *reinterpret_cast<const f32x4*>(cw + o * 64 + 8 * g);
        f32x4 q  = *reinterpret_cast<const f32x4*>(cw + o * 64 + 8 * g + 4);
        f32x4 p2 = *reinterpret_cast<const f32x4*>(cw + o * 64 + 32 + 8 * g);
        f32x4 q2 = *reinterpret_cast<const f32x4*>(cw + o * 64 + 32 + 8 * g + 4);
        size_t zoff = (((size_t)b * 64 + o) * 256 + h) * 16 + 4 * g;
        f32x4 zr = *reinterpret_cast<const f32x4*>(Zr + zoff);
        f32x4 zi = *reinterpret_cast<const f32x4*>(Zi + zoff);
#pragma unroll
        for (int t = 0; t < 4; ++t) {
            a0[t]     = (short)f2bf(p[t]);  a0[t + 4] = (short)f2bf(q[t]);
            a1[t]     = (short)f2bf(p2[t]); a1[t + 4] = (short)f2bf(q2[t]);
            az[2 * t]     = (short)f2bf(zr[t]);   // k=64+2ky   -> Zr[ky]
            az[2 * t + 1] = (short)f2bf(zi[t]);   // k=64+2ky+1 -> Zi[ky]
        }
    }
    s16x8 btr[8];
#pragma unroll
    for (int f = 0; f < 8; ++f) {
        int w = (f0 + f) * 16 + m;
        btr[f] = *reinterpret_cast<const s16x8*>(ttab + w * 32 + 8 * g);
    }
    f32x4 bv = *reinterpret_cast<const f32x4*>(bias + o0 + 4 * g);

    // ---- LDS writes: pair (x[2ip][w], x[2ip+1][w]) -> word ip of row w ----
#pragma unroll
    for (int it = 0; it < 4; ++it) {
        int ip = it * 8 + (tid >> 6);
        const float* pa = reinterpret_cast<const float*>(&va[it]);
        const float* pb = reinterpret_cast<const float*>(&vb[it]);
#pragma unroll
        for (int j = 0; j < 4; ++j) {
            int w = w0s + j;
            int c = (w ^ (w >> 3)) & 7;
            unsigned pk = (unsigned)f2bf(pa[j]) | ((unsigned)f2bf(pb[j]) << 16);
            bsx[(w << 5) + ((((ip >> 2) ^ c) << 2) | (ip & 3))] = pk;
        }
    }
    __syncthreads();

    // ---- main: per w-frag, 2 conv k-steps (LDS) + 1 spectral k-step (regs) ----
    f32x4 acc[8];
#pragma unroll
    for (int f = 0; f < 8; ++f)
#pragma unroll
        for (int r = 0; r < 4; ++r) acc[f][r] = 0.f;

#pragma unroll
    for (int f = 0; f < 8; ++f) {
        int w = (f0 + f) * 16 + m;
        int c = (w ^ (w >> 3)) & 7;
        const char* rb = reinterpret_cast<const char*>(bsx) + (w << 7);
        s16x8 bx0 = *reinterpret_cast<const s16x8*>(rb + ((g ^ c) << 4));
        s16x8 bx1 = *reinterpret_cast<const s16x8*>(rb + (((4 + g) ^ c) << 4));
        acc[f] = __builtin_amdgcn_mfma_f32_16x16x32_bf16(a0, bx0, acc[f], 0, 0, 0);
        acc[f] = __builtin_amdgcn_mfma_f32_16x16x32_bf16(a1, bx1, acc[f], 0, 0, 0);
        acc[f] = __builtin_amdgcn_mfma_f32_16x16x32_bf16(az, btr[f], acc[f], 0, 0, 0);
    }

    // ---- epilogue: bias + store (row o = o0+4g+r, col w; 64B segments) ----
    float* ob = out + ((size_t)b * 64 + o0 + 4 * g) * 65536 + (size_t)h * 256;
#pragma unroll
    for (int f = 0; f < 8; ++f) {
        int wb = (f0 + f) * 16 + m;
#pragma unroll
        for (int r = 0; r < 4; ++r)
            ob[(size_t)r * 65536 + wb] = acc[f][r] + bv[r];
    }
}

extern "C" void kernel_launch(void* const* d_in, const int* in_sizes, int n_in,
                              void* d_out, int out_size, void* d_ws, size_t ws_size,
                              hipStream_t stream) {
    const float* x   = (const float*)d_in[0];
    const float* w1r = (const float*)d_in[1];
    const float* w1i = (const float*)d_in[2];
    const float* w2r = (const float*)d_in[3];
    const float* w2i = (const float*)d_in[4];
    const float* cw  = (const float*)d_in[5];
    const float* cb  = (const float*)d_in[6];
    float* out = (float*)d_out;
    float* ws  = (float*)d_ws;
    unsigned short* ttab = (unsigned short*)(ws + O_TT);

    ka_fwd_w<<<512, 256, 0, stream>>>(x, ws + O_UR, ws + O_UI);
    kb_fwd_h<<<512, 256, 0, stream>>>(ws + O_UR, ws + O_UI, ws + O_XR, ws + O_XI);
    kw_prep<<<256, 256, 0, stream>>>(w1r, w1i, w2r, w2i, ws + O_WTR, ws + O_WTI);
    ktrig<<<32, 256, 0, stream>>>(ttab);
    kc_mix<<<512, 256, 0, stream>>>(ws + O_XR, ws + O_XI, ws + O_WTR, ws + O_WTI,
                                    ws + O_YR, ws + O_YI);
    kd_inv_h<<<512, 256, 0, stream>>>(ws + O_YR, ws + O_YI, ws + O_ZR, ws + O_ZI);
    ke_mfma<<<2048, 512, 0, stream>>>(x, ws + O_ZR, ws + O_ZI, cw, cb, ttab, out);
}

// Round 7
// 162.986 us; speedup vs baseline: 1.4715x; 1.1214x over previous
//
#include <hip/hip_runtime.h>
#include <math.h>

// FourierLayer: B=8, C=64, H=256, W=256, M1=M2=16.
// Pipeline:
//   AB (fused MFMA): per bc:
//     phase1: U[32][256h] = TA[32][256w] . B1[w][h]=x[h][w]   (bf16 MFMA, K-chunked)
//             rows 0-15 = Ur(ky), 16-31 = Ui(ky); TA includes 1/256 ortho norm
//     phase2: X[64][16ky] = TB[64][512] . U2[2h+p][ky]        (bf16 MFMA)
//             rows 0-31 = Xr(kxi), 32-63 = Xi(kxi); k interleaves (Ur,Ui) per h
//   Wprep: Wt[kxi][ky][i][o] = (kxi<16 ? w1 : w2)[i][o][kxi&15][ky]
//   C: Y[b][o][kxi][ky] = sum_i X[b][i][kxi][ky] * Wt[kxi][ky][i][o]  (complex, f32)
//   D: Z'[b][o][h][ky] = prescale * (1/256) * sum_kxi Y * e^{+2pi i kx h/256}
//   E (MFMA): out[64o][256w] = [cw | Z'] (64x96 bf16) @ [x ; trig] (96x256 bf16) + bias

#define TWOPI_256 0.024543692606170259f   // 2*pi/256
#define INV256    0.00390625f

// ---------------- workspace layout (floats) ----------------
#define NX   262144             // 8*64*32*16
#define NWT  2097152            // 32*16*64*64
#define NZ   2097152            // 8*64*256*16
#define O_TA  0                 // 8192 ushort  (32x256 bf16)  = 4096 float slots
#define O_TB  4096              // 32768 ushort (64x512 bf16)  = 16384 float slots
#define O_XR  20480
#define O_XI  (O_XR + NX)
#define O_WTR (O_XI + NX)
#define O_WTI (O_WTR + NWT)
#define O_YR  (O_WTI + NWT)
#define O_YI  (O_YR + NX)
#define O_ZR  (O_YI + NX)
#define O_ZI  (O_ZR + NZ)
#define O_TT  (O_ZI + NZ)       // E trig table: 8192 ushort = 4096 float slots

using s16x8 = __attribute__((ext_vector_type(8))) short;   // 8 bf16 (4 VGPRs)
using f32x4 = __attribute__((ext_vector_type(4))) float;   // MFMA acc

__device__ __forceinline__ unsigned short f2bf(float f) {  // RNE f32->bf16
    union { float f; unsigned u; } a; a.f = f;
    unsigned r = (a.u + 0x7fffu + ((a.u >> 16) & 1u)) >> 16;
    return (unsigned short)r;
}

// ---------------- table gen: TA (phase1) + TB (phase2) ----------------
__global__ __launch_bounds__(256) void ktabs(unsigned short* __restrict__ tA,
                                             unsigned short* __restrict__ tB) {
    int idx = blockIdx.x * 256 + threadIdx.x;     // 40960 total
    if (idx < 8192) {
        // TA[col][w]: col<16 -> cos(2pi col w/256)/256 ; col>=16 -> -sin(...)/256
        int col = idx >> 8, w = idx & 255;
        int ky = col & 15;
        int mm = (ky * w) & 255;
        float s, c; sincosf((float)mm * TWOPI_256, &s, &c);
        tA[idx] = f2bf(col < 16 ? c * INV256 : -s * INV256);
    } else if (idx < 40960) {
        // TB[kx2][2h+p]: kx2<32 (Re rows): p0=cos, p1=sin ; kx2>=32 (Im): p0=-sin, p1=cos
        int j = idx - 8192;
        int kx2 = j >> 9, k = j & 511, h = k >> 1, p = k & 1;
        int kxi = kx2 & 31;
        int kx = (kxi < 16) ? kxi : (224 + kxi);
        int mm = (kx * h) & 255;
        float s, c; sincosf((float)mm * TWOPI_256, &s, &c);
        float v;
        if (kx2 < 32) v = p ? s : c;
        else          v = p ? c : -s;
        tB[j] = f2bf(v);
    }
}

// ---------------- Kernel AB (fused MFMA): x -> X ----------------
// grid 512 (bc), block 256 (4 waves). Wave owns h-band of 64 in phase 1,
// one 16-row M-frag (fm2 = wave) in phase 2.
__global__ __launch_bounds__(256) void kab_fwd(const float* __restrict__ x,
                                               const unsigned short* __restrict__ tA,
                                               const unsigned short* __restrict__ tB,
                                               float* __restrict__ Xr,
                                               float* __restrict__ Xi) {
    __shared__ __align__(16) unsigned short xt[16384];  // 32 KB [256h][64w] bf16 swz
    __shared__ __align__(16) unsigned int   ub[4096];   // 16 KB U2 [16ky][512k] swz
    const int tid  = threadIdx.x;
    const int bc   = blockIdx.x;
    const int m    = tid & 15;
    const int g    = (tid >> 4) & 3;
    const int wave = tid >> 6;

    const float* xp = x + (size_t)bc * 65536;

    f32x4 acc[2][4];     // [fm (Ur/Ui)] [fn (h sub-tile)]
#pragma unroll
    for (int a = 0; a < 2; ++a)
#pragma unroll
        for (int fn = 0; fn < 4; ++fn)
#pragma unroll
            for (int r = 0; r < 4; ++r) acc[a][fn][r] = 0.f;

    for (int ch = 0; ch < 4; ++ch) {
        // ---- stage x chunk [256h][64w] as bf16, 16B-block XOR swizzle by h&7 ----
#pragma unroll
        for (int it = 0; it < 16; ++it) {
            int h  = it * 16 + (tid >> 4);
            int w4 = tid & 15;
            float4 v = *reinterpret_cast<const float4*>(xp + h * 256 + ch * 64 + w4 * 4);
            unsigned lo = (unsigned)f2bf(v.x) | ((unsigned)f2bf(v.y) << 16);
            unsigned hi = (unsigned)f2bf(v.z) | ((unsigned)f2bf(v.w) << 16);
            int wl  = w4 * 4;
            int blk = (wl >> 3) ^ (h & 7);
            char* p = reinterpret_cast<char*>(xt) + (h << 7) + (blk << 4) + ((wl & 7) << 1);
            *reinterpret_cast<uint2*>(p) = make_uint2(lo, hi);
        }
        __syncthreads();
        // ---- phase-1 MFMA: 2 k-steps per chunk ----
#pragma unroll
        for (int ks = 0; ks < 2; ++ks) {
            s16x8 a0 = *reinterpret_cast<const s16x8*>(tA + m * 256        + ch * 64 + ks * 32 + 8 * g);
            s16x8 a1 = *reinterpret_cast<const s16x8*>(tA + (16 + m) * 256 + ch * 64 + ks * 32 + 8 * g);
#pragma unroll
            for (int fn = 0; fn < 4; ++fn) {
                int h   = wave * 64 + fn * 16 + m;
                int blk = (4 * ks + g) ^ (h & 7);
                s16x8 bf = *reinterpret_cast<const s16x8*>(
                    reinterpret_cast<const char*>(xt) + (h << 7) + (blk << 4));
                acc[0][fn] = __builtin_amdgcn_mfma_f32_16x16x32_bf16(a0, bf, acc[0][fn], 0, 0, 0);
                acc[1][fn] = __builtin_amdgcn_mfma_f32_16x16x32_bf16(a1, bf, acc[1][fn], 0, 0, 0);
            }
        }
        __syncthreads();
    }

    // ---- redistribute U -> ub: word h of row ky holds (Ur,Ui) bf16 pair ----
    // D1 frag: lane(m,g) reg r holds U[fm*16+4g+r][wave*64+fn*16+m]
#pragma unroll
    for (int fn = 0; fn < 4; ++fn) {
        int h = wave * 64 + fn * 16 + m;
#pragma unroll
        for (int r = 0; r < 4; ++r) {
            int ky = 4 * g + r;
            unsigned pk = (unsigned)f2bf(acc[0][fn][r]) | ((unsigned)f2bf(acc[1][fn][r]) << 16);
            int blk = (h >> 2) ^ (ky & 7);
            ub[ky * 256 + blk * 4 + (h & 3)] = pk;
        }
    }
    __syncthreads();

    // ---- phase-2 MFMA: X[64][16] = TB[64][512] . U2[512][16] ----
    f32x4 acc2;
#pragma unroll
    for (int r = 0; r < 4; ++r) acc2[r] = 0.f;
#pragma unroll
    for (int ks = 0; ks < 16; ++ks) {
        s16x8 a2 = *reinterpret_cast<const s16x8*>(tB + (wave * 16 + m) * 512 + ks * 32 + 8 * g);
        int blk = (4 * ks + g) ^ (m & 7);
        s16x8 b2 = *reinterpret_cast<const s16x8*>(
            reinterpret_cast<const char*>(ub) + m * 1024 + (blk << 4));
        acc2 = __builtin_amdgcn_mfma_f32_16x16x32_bf16(a2, b2, acc2, 0, 0, 0);
    }
    // D2 frag: lane(m,g) reg r = X[wave*16+4g+r][ky=m]
#pragma unroll
    for (int r = 0; r < 4; ++r) {
        int kx2 = wave * 16 + 4 * g + r;
        if (kx2 < 32) Xr[(size_t)bc * 512 + kx2 * 16 + m]        = acc2[r];
        else          Xi[(size_t)bc * 512 + (kx2 - 32) * 16 + m] = acc2[r];
    }
}

// ---------------- Kernel Wprep: weight transpose --------------
__global__ __launch_bounds__(256) void kw_prep(const float* __restrict__ w1r,
                                               const float* __restrict__ w1i,
                                               const float* __restrict__ w2r,
                                               const float* __restrict__ w2i,
                                               float* __restrict__ Wtr,
                                               float* __restrict__ Wti) {
    __shared__ float lds[128][65];
    const int tid = threadIdx.x;
    const int a = blockIdx.x >> 6;
    const int i = blockIdx.x & 63;
    const float* src = (a == 0) ? w1r : (a == 1) ? w1i : (a == 2) ? w2r : w2i;
    float* dst = (a & 1) ? Wti : Wtr;
    const int kxoff = (a >> 1) << 4;
    const float* sp = src + (size_t)i * 16384;

    for (int p = 0; p < 2; ++p) {
        if (p) __syncthreads();
#pragma unroll
        for (int it = 0; it < 8; ++it) {
            int f4 = it * 256 + tid;
            int o = f4 >> 5, j4 = f4 & 31;
            float4 v = *reinterpret_cast<const float4*>(sp + o * 256 + p * 128 + j4 * 4);
            lds[j4 * 4 + 0][o] = v.x; lds[j4 * 4 + 1][o] = v.y;
            lds[j4 * 4 + 2][o] = v.z; lds[j4 * 4 + 3][o] = v.w;
        }
        __syncthreads();
        const int o = tid & 63, mq = tid >> 6;
#pragma unroll
        for (int r = 0; r < 32; ++r) {
            int lm = r * 4 + mq;
            int mky = p * 128 + lm;
            int mm = mky >> 4, ky = mky & 15;
            dst[((((size_t)(kxoff + mm)) * 16 + ky) * 64 + i) * 64 + o] = lds[lm][o];
        }
    }
}

// trig table for E: ttab[w][kk] bf16, kk=2*ky+c: c==0 -> cos(2pi ky w/256), c==1 -> -sin
__global__ __launch_bounds__(256) void ktrig(unsigned short* __restrict__ ttab) {
    int idx = blockIdx.x * 256 + threadIdx.x;    // 8192 = 256 w x 32 kk
    int w = idx >> 5, kk = idx & 31, ky = kk >> 1;
    int mm = (ky * w) & 255;
    float s, c;
    sincosf((float)mm * TWOPI_256, &s, &c);
    ttab[idx] = f2bf((kk & 1) ? -s : c);
}

// ---------------- Kernel C: channel mixing --------------
__global__ __launch_bounds__(256) void kc_mix(const float* __restrict__ Xr,
                                              const float* __restrict__ Xi,
                                              const float* __restrict__ Wtr,
                                              const float* __restrict__ Wti,
                                              float* __restrict__ Yr,
                                              float* __restrict__ Yi) {
    __shared__ float xsr[512], xsi[512];
    const int tid = threadIdx.x;
    const int mode = blockIdx.x;
#pragma unroll
    for (int r = 0; r < 2; ++r) {
        int bi = r * 256 + tid;
        xsr[bi] = Xr[(size_t)bi * 512 + mode];
        xsi[bi] = Xi[(size_t)bi * 512 + mode];
    }
    __syncthreads();
    const int o = tid & 63, bg = tid >> 6;
    float yr0 = 0.f, yi0 = 0.f, yr1 = 0.f, yi1 = 0.f;
    const float* wrp = Wtr + (size_t)mode * 4096;
    const float* wip = Wti + (size_t)mode * 4096;
#pragma unroll 8
    for (int i = 0; i < 64; ++i) {
        float wr = wrp[i * 64 + o], wi = wip[i * 64 + o];
        float xr = xsr[bg * 64 + i],        xi = xsi[bg * 64 + i];
        yr0 += xr * wr - xi * wi;  yi0 += xr * wi + xi * wr;
        float xr2 = xsr[(bg + 4) * 64 + i], xi2 = xsi[(bg + 4) * 64 + i];
        yr1 += xr2 * wr - xi2 * wi;  yi1 += xr2 * wi + xi2 * wr;
    }
    Yr[((size_t)bg * 64 + o) * 512 + mode]       = yr0;
    Yi[((size_t)bg * 64 + o) * 512 + mode]       = yi0;
    Yr[((size_t)(bg + 4) * 64 + o) * 512 + mode] = yr1;
    Yi[((size_t)(bg + 4) * 64 + o) * 512 + mode] = yi1;
}

// ---------------- Kernel D: inverse h-transform --------------
__global__ __launch_bounds__(256) void kd_inv_h(const float* __restrict__ Yr,
                                                const float* __restrict__ Yi,
                                                float* __restrict__ Zr,
                                                float* __restrict__ Zi) {
    __shared__ __align__(16) float2 ysz[512];
    const int tid = threadIdx.x;
    const int bo = blockIdx.x;
#pragma unroll
    for (int r = 0; r < 2; ++r) {
        int mm = r * 256 + tid;
        ysz[mm] = make_float2(Yr[(size_t)bo * 512 + mm], Yi[(size_t)bo * 512 + mm]);
    }
    __syncthreads();
    const int h = tid;
    float stepS, stepC;
    sincosf((float)h * TWOPI_256, &stepS, &stepC);
    float accR[16], accI[16];
#pragma unroll
    for (int k = 0; k < 16; ++k) { accR[k] = 0.f; accI[k] = 0.f; }
    float tre = 1.f, tim = 0.f;
    for (int kxi = 0; kxi < 32; ++kxi) {
        if (kxi == 16) {
            int m0 = (240 * h) & 255;
            sincosf((float)m0 * TWOPI_256, &tim, &tre);
        }
        const float4* yp = reinterpret_cast<const float4*>(&ysz[kxi * 16]);
#pragma unroll
        for (int k2 = 0; k2 < 8; ++k2) {
            float4 y = yp[k2];
            accR[2 * k2]     += y.x * tre - y.y * tim;
            accI[2 * k2]     += y.x * tim + y.y * tre;
            accR[2 * k2 + 1] += y.z * tre - y.w * tim;
            accI[2 * k2 + 1] += y.z * tim + y.w * tre;
        }
        float nre = tre * stepC - tim * stepS;
        float nim = tre * stepS + tim * stepC;
        tre = nre; tim = nim;
    }
    const float s1 = INV256, s2 = 2.f * INV256;
    float* zrp = Zr + ((size_t)bo * 256 + h) * 16;
    float* zip = Zi + ((size_t)bo * 256 + h) * 16;
    float4 r0 = {accR[0] * s1,  accR[1] * s2,  accR[2] * s2,  accR[3] * s2};
    float4 r1 = {accR[4] * s2,  accR[5] * s2,  accR[6] * s2,  accR[7] * s2};
    float4 r2 = {accR[8] * s2,  accR[9] * s2,  accR[10] * s2, accR[11] * s2};
    float4 r3 = {accR[12] * s2, accR[13] * s2, accR[14] * s2, accR[15] * s2};
    float4 i0 = {0.f,           accI[1] * s2,  accI[2] * s2,  accI[3] * s2};
    float4 i1 = {accI[4] * s2,  accI[5] * s2,  accI[6] * s2,  accI[7] * s2};
    float4 i2 = {accI[8] * s2,  accI[9] * s2,  accI[10] * s2, accI[11] * s2};
    float4 i3 = {accI[12] * s2, accI[13] * s2, accI[14] * s2, accI[15] * s2};
    reinterpret_cast<float4*>(zrp)[0] = r0; reinterpret_cast<float4*>(zrp)[1] = r1;
    reinterpret_cast<float4*>(zrp)[2] = r2; reinterpret_cast<float4*>(zrp)[3] = r3;
    reinterpret_cast<float4*>(zip)[0] = i0; reinterpret_cast<float4*>(zip)[1] = i1;
    reinterpret_cast<float4*>(zip)[2] = i2; reinterpret_cast<float4*>(zip)[3] = i3;
}

// ---------------- Kernel E (MFMA): out = [cw|Z'] @ [x;trig] + bias ----------
__global__ __launch_bounds__(512) void ke_mfma(const float* __restrict__ x,
                                               const float* __restrict__ Zr,
                                               const float* __restrict__ Zi,
                                               const float* __restrict__ cw,
                                               const float* __restrict__ bias,
                                               const unsigned short* __restrict__ ttab,
                                               float* __restrict__ out) {
    __shared__ unsigned int bsx[8192];   // 32 KB: [w=256][16 words], swizzled
    const int tid = threadIdx.x;
    const int b = blockIdx.x >> 8;
    const int h = blockIdx.x & 255;

    const size_t xbase = ((size_t)b * 64) * 65536 + (size_t)h * 256;
    const int w0s = (tid & 63) * 4;
    float4 va[4], vb[4];
#pragma unroll
    for (int it = 0; it < 4; ++it) {
        int ip = it * 8 + (tid >> 6);
        va[it] = *reinterpret_cast<const float4*>(x + xbase + (size_t)(2 * ip) * 65536 + w0s);
        vb[it] = *reinterpret_cast<const float4*>(x + xbase + (size_t)(2 * ip + 1) * 65536 + w0s);
    }

    const int m = tid & 15;
    const int g = (tid >> 4) & 3;
    const int wave = tid >> 6;
    const int o0 = (wave >> 1) * 16;
    const int f0 = (wave & 1) * 8;
    const int o = o0 + m;

    s16x8 a0, a1, az;
    {
        f32x4 p  = *reinterpret_cast<const f32x4*>(cw + o * 64 + 8 * g);
        f32x4 q  = *reinterpret_cast<const f32x4*>(cw + o * 64 + 8 * g + 4);
        f32x4 p2 = *reinterpret_cast<const f32x4*>(cw + o * 64 + 32 + 8 * g);
        f32x4 q2 = *reinterpret_cast<const f32x4*>(cw + o * 64 + 32 + 8 * g + 4);
        size_t zoff = (((size_t)b * 64 + o) * 256 + h) * 16 + 4 * g;
        f32x4 zr = *reinterpret_cast<const f32x4*>(Zr + zoff);
        f32x4 zi = *reinterpret_cast<const f32x4*>(Zi + zoff);
#pragma unroll
        for (int t = 0; t < 4; ++t) {
            a0[t]     = (short)f2bf(p[t]);  a0[t + 4] = (short)f2bf(q[t]);
            a1[t]     = (short)f2bf(p2[t]); a1[t + 4] = (short)f2bf(q2[t]);
            az[2 * t]     = (short)f2bf(zr[t]);
            az[2 * t + 1] = (short)f2bf(zi[t]);
        }
    }
    s16x8 btr[8];
#pragma unroll
    for (int f = 0; f < 8; ++f) {
        int w = (f0 + f) * 16 + m;
        btr[f] = *reinterpret_cast<const s16x8*>(ttab + w * 32 + 8 * g);
    }
    f32x4 bv = *reinterpret_cast<const f32x4*>(bias + o0 + 4 * g);

#pragma unroll
    for (int it = 0; it < 4; ++it) {
        int ip = it * 8 + (tid >> 6);
        const float* pa = reinterpret_cast<const float*>(&va[it]);
        const float* pb = reinterpret_cast<const float*>(&vb[it]);
#pragma unroll
        for (int j = 0; j < 4; ++j) {
            int w = w0s + j;
            int c = (w ^ (w >> 3)) & 7;
            unsigned pk = (unsigned)f2bf(pa[j]) | ((unsigned)f2bf(pb[j]) << 16);
            bsx[(w << 5) + ((((ip >> 2) ^ c) << 2) | (ip & 3))] = pk;
        }
    }
    __syncthreads();

    f32x4 acc[8];
#pragma unroll
    for (int f = 0; f < 8; ++f)
#pragma unroll
        for (int r = 0; r < 4; ++r) acc[f][r] = 0.f;

#pragma unroll
    for (int f = 0; f < 8; ++f) {
        int w = (f0 + f) * 16 + m;
        int c = (w ^ (w >> 3)) & 7;
        const char* rb = reinterpret_cast<const char*>(bsx) + (w << 7);
        s16x8 bx0 = *reinterpret_cast<const s16x8*>(rb + ((g ^ c) << 4));
        s16x8 bx1 = *reinterpret_cast<const s16x8*>(rb + (((4 + g) ^ c) << 4));
        acc[f] = __builtin_amdgcn_mfma_f32_16x16x32_bf16(a0, bx0, acc[f], 0, 0, 0);
        acc[f] = __builtin_amdgcn_mfma_f32_16x16x32_bf16(a1, bx1, acc[f], 0, 0, 0);
        acc[f] = __builtin_amdgcn_mfma_f32_16x16x32_bf16(az, btr[f], acc[f], 0, 0, 0);
    }

    float* ob = out + ((size_t)b * 64 + o0 + 4 * g) * 65536 + (size_t)h * 256;
#pragma unroll
    for (int f = 0; f < 8; ++f) {
        int wb = (f0 + f) * 16 + m;
#pragma unroll
        for (int r = 0; r < 4; ++r)
            ob[(size_t)r * 65536 + wb] = acc[f][r] + bv[r];
    }
}

extern "C" void kernel_launch(void* const* d_in, const int* in_sizes, int n_in,
                              void* d_out, int out_size, void* d_ws, size_t ws_size,
                              hipStream_t stream) {
    const float* x   = (const float*)d_in[0];
    const float* w1r = (const float*)d_in[1];
    const float* w1i = (const float*)d_in[2];
    const float* w2r = (const float*)d_in[3];
    const float* w2i = (const float*)d_in[4];
    const float* cw  = (const float*)d_in[5];
    const float* cb  = (const float*)d_in[6];
    float* out = (float*)d_out;
    float* ws  = (float*)d_ws;
    unsigned short* tA   = (unsigned short*)(ws + O_TA);
    unsigned short* tB   = (unsigned short*)(ws + O_TB);
    unsigned short* ttab = (unsigned short*)(ws + O_TT);

    ktabs<<<160, 256, 0, stream>>>(tA, tB);
    ktrig<<<32, 256, 0, stream>>>(ttab);
    kw_prep<<<256, 256, 0, stream>>>(w1r, w1i, w2r, w2i, ws + O_WTR, ws + O_WTI);
    kab_fwd<<<512, 256, 0, stream>>>(x, tA, tB, ws + O_XR, ws + O_XI);
    kc_mix<<<512, 256, 0, stream>>>(ws + O_XR, ws + O_XI, ws + O_WTR, ws + O_WTI,
                                    ws + O_YR, ws + O_YI);
    kd_inv_h<<<512, 256, 0, stream>>>(ws + O_YR, ws + O_YI, ws + O_ZR, ws + O_ZI);
    ke_mfma<<<2048, 512, 0, stream>>>(x, ws + O_ZR, ws + O_ZI, cw, cb, ttab, out);
}

// Round 8
// 147.321 us; speedup vs baseline: 1.6280x; 1.1063x over previous
//
#include <hip/hip_runtime.h>
#include <math.h>

// FourierLayer: B=8, C=64, H=256, W=256, M1=M2=16.
// Pipeline:
//   AB (fused MFMA): per bc: phase1 U[32][256h] = TA . x^T ; phase2 X[64][16ky] = TB . U2
//   Wprep: Wt[kxi][ky][i][o] = (kxi<16 ? w1 : w2)[i][o][kxi&15][ky]
//   C: Y2[b][o][ky][kxi] = sum_i X[b][i][kxi][ky] * Wt[kxi][ky][i][o]  (complex, f32)
//   D (MFMA): Z[b][o][h][ky] = sum_kxi sc(ky)*(Yr,Yi).(trig) ; per b: [1024 m][64 k][256 h]
//   E (MFMA): out[64o][256w] = [cw | Z] (64x96 bf16) @ [x ; trig] (96x256 bf16) + bias

#define TWOPI_256 0.024543692606170259f   // 2*pi/256
#define INV256    0.00390625f

// ---------------- workspace layout (floats) ----------------
#define NX   262144             // 8*64*32*16
#define NWT  2097152            // 32*16*64*64
#define NZ   2097152            // 8*64*256*16
#define O_TA  0                 // 8192 ushort  (32x256 bf16)
#define O_TB  4096              // 32768 ushort (64x512 bf16)
#define O_XR  20480
#define O_XI  (O_XR + NX)
#define O_WTR (O_XI + NX)
#define O_WTI (O_WTR + NWT)
#define O_YR  (O_WTI + NWT)
#define O_YI  (O_YR + NX)
#define O_ZR  (O_YI + NX)
#define O_ZI  (O_ZR + NZ)
#define O_TT  (O_ZI + NZ)       // E trig table: 8192 ushort
#define O_TD  (O_TT + 4096)     // D trig table: 32768 ushort ([2 ri][256 h][64 k])

using s16x8 = __attribute__((ext_vector_type(8))) short;   // 8 bf16 (4 VGPRs)
using f32x4 = __attribute__((ext_vector_type(4))) float;   // MFMA acc

__device__ __forceinline__ unsigned short f2bf(float f) {  // RNE f32->bf16
    union { float f; unsigned u; } a; a.f = f;
    unsigned r = (a.u + 0x7fffu + ((a.u >> 16) & 1u)) >> 16;
    return (unsigned short)r;
}

// ---------------- table gen: TA (AB ph1) + TB (AB ph2) + TD (D) ----------------
__global__ __launch_bounds__(256) void ktabs(unsigned short* __restrict__ tA,
                                             unsigned short* __restrict__ tB,
                                             unsigned short* __restrict__ tD) {
    int idx = blockIdx.x * 256 + threadIdx.x;     // 73728 total
    if (idx < 8192) {
        // TA[col][w]: col<16 -> cos(2pi col w/256)/256 ; col>=16 -> -sin(...)/256
        int col = idx >> 8, w = idx & 255;
        int ky = col & 15;
        int mm = (ky * w) & 255;
        float s, c; sincosf((float)mm * TWOPI_256, &s, &c);
        tA[idx] = f2bf(col < 16 ? c * INV256 : -s * INV256);
    } else if (idx < 40960) {
        // TB[kx2][2h+p]: kx2<32 (Re rows): p0=cos, p1=sin ; kx2>=32 (Im): p0=-sin, p1=cos
        int j = idx - 8192;
        int kx2 = j >> 9, k = j & 511, h = k >> 1, p = k & 1;
        int kxi = kx2 & 31;
        int kx = (kxi < 16) ? kxi : (224 + kxi);
        int mm = (kx * h) & 255;
        float s, c; sincosf((float)mm * TWOPI_256, &s, &c);
        float v;
        if (kx2 < 32) v = p ? s : c;
        else          v = p ? c : -s;
        tB[j] = f2bf(v);
    } else {
        // TD[ri][h][k=2kxi+p], e^{+2pi i kx h/256}:
        //   ri=0 (Zr): p0 = cos, p1 = -sin ; ri=1 (Zi): p0 = sin, p1 = cos
        int j = idx - 40960;
        int ri = j >> 14, rem = j & 16383;
        int h = rem >> 6, k = rem & 63, kxi = k >> 1, p = k & 1;
        int kx = (kxi < 16) ? kxi : (224 + kxi);
        int mm = (kx * h) & 255;
        float s, c; sincosf((float)mm * TWOPI_256, &s, &c);
        float v;
        if (ri == 0) v = p ? -s : c;
        else         v = p ? c : s;
        tD[j] = f2bf(v);
    }
}

// ---------------- Kernel AB (fused MFMA): x -> X ----------------
__global__ __launch_bounds__(256) void kab_fwd(const float* __restrict__ x,
                                               const unsigned short* __restrict__ tA,
                                               const unsigned short* __restrict__ tB,
                                               float* __restrict__ Xr,
                                               float* __restrict__ Xi) {
    __shared__ __align__(16) unsigned short xt[16384];  // 32 KB [256h][64w] bf16 swz
    __shared__ __align__(16) unsigned int   ub[4096];   // 16 KB U2 [16ky][512k] swz
    const int tid  = threadIdx.x;
    const int bc   = blockIdx.x;
    const int m    = tid & 15;
    const int g    = (tid >> 4) & 3;
    const int wave = tid >> 6;

    const float* xp = x + (size_t)bc * 65536;

    f32x4 acc[2][4];
#pragma unroll
    for (int a = 0; a < 2; ++a)
#pragma unroll
        for (int fn = 0; fn < 4; ++fn)
#pragma unroll
            for (int r = 0; r < 4; ++r) acc[a][fn][r] = 0.f;

    for (int ch = 0; ch < 4; ++ch) {
#pragma unroll
        for (int it = 0; it < 16; ++it) {
            int h  = it * 16 + (tid >> 4);
            int w4 = tid & 15;
            float4 v = *reinterpret_cast<const float4*>(xp + h * 256 + ch * 64 + w4 * 4);
            unsigned lo = (unsigned)f2bf(v.x) | ((unsigned)f2bf(v.y) << 16);
            unsigned hi = (unsigned)f2bf(v.z) | ((unsigned)f2bf(v.w) << 16);
            int wl  = w4 * 4;
            int blk = (wl >> 3) ^ (h & 7);
            char* p = reinterpret_cast<char*>(xt) + (h << 7) + (blk << 4) + ((wl & 7) << 1);
            *reinterpret_cast<uint2*>(p) = make_uint2(lo, hi);
        }
        __syncthreads();
#pragma unroll
        for (int ks = 0; ks < 2; ++ks) {
            s16x8 a0 = *reinterpret_cast<const s16x8*>(tA + m * 256        + ch * 64 + ks * 32 + 8 * g);
            s16x8 a1 = *reinterpret_cast<const s16x8*>(tA + (16 + m) * 256 + ch * 64 + ks * 32 + 8 * g);
#pragma unroll
            for (int fn = 0; fn < 4; ++fn) {
                int h   = wave * 64 + fn * 16 + m;
                int blk = (4 * ks + g) ^ (h & 7);
                s16x8 bf = *reinterpret_cast<const s16x8*>(
                    reinterpret_cast<const char*>(xt) + (h << 7) + (blk << 4));
                acc[0][fn] = __builtin_amdgcn_mfma_f32_16x16x32_bf16(a0, bf, acc[0][fn], 0, 0, 0);
                acc[1][fn] = __builtin_amdgcn_mfma_f32_16x16x32_bf16(a1, bf, acc[1][fn], 0, 0, 0);
            }
        }
        __syncthreads();
    }

#pragma unroll
    for (int fn = 0; fn < 4; ++fn) {
        int h = wave * 64 + fn * 16 + m;
#pragma unroll
        for (int r = 0; r < 4; ++r) {
            int ky = 4 * g + r;
            unsigned pk = (unsigned)f2bf(acc[0][fn][r]) | ((unsigned)f2bf(acc[1][fn][r]) << 16);
            int blk = (h >> 2) ^ (ky & 7);
            ub[ky * 256 + blk * 4 + (h & 3)] = pk;
        }
    }
    __syncthreads();

    f32x4 acc2;
#pragma unroll
    for (int r = 0; r < 4; ++r) acc2[r] = 0.f;
#pragma unroll
    for (int ks = 0; ks < 16; ++ks) {
        s16x8 a2 = *reinterpret_cast<const s16x8*>(tB + (wave * 16 + m) * 512 + ks * 32 + 8 * g);
        int blk = (4 * ks + g) ^ (m & 7);
        s16x8 b2 = *reinterpret_cast<const s16x8*>(
            reinterpret_cast<const char*>(ub) + m * 1024 + (blk << 4));
        acc2 = __builtin_amdgcn_mfma_f32_16x16x32_bf16(a2, b2, acc2, 0, 0, 0);
    }
#pragma unroll
    for (int r = 0; r < 4; ++r) {
        int kx2 = wave * 16 + 4 * g + r;
        if (kx2 < 32) Xr[(size_t)bc * 512 + kx2 * 16 + m]        = acc2[r];
        else          Xi[(size_t)bc * 512 + (kx2 - 32) * 16 + m] = acc2[r];
    }
}

// ---------------- Kernel Wprep: weight transpose --------------
__global__ __launch_bounds__(256) void kw_prep(const float* __restrict__ w1r,
                                               const float* __restrict__ w1i,
                                               const float* __restrict__ w2r,
                                               const float* __restrict__ w2i,
                                               float* __restrict__ Wtr,
                                               float* __restrict__ Wti) {
    __shared__ float lds[128][65];
    const int tid = threadIdx.x;
    const int a = blockIdx.x >> 6;
    const int i = blockIdx.x & 63;
    const float* src = (a == 0) ? w1r : (a == 1) ? w1i : (a == 2) ? w2r : w2i;
    float* dst = (a & 1) ? Wti : Wtr;
    const int kxoff = (a >> 1) << 4;
    const float* sp = src + (size_t)i * 16384;

    for (int p = 0; p < 2; ++p) {
        if (p) __syncthreads();
#pragma unroll
        for (int it = 0; it < 8; ++it) {
            int f4 = it * 256 + tid;
            int o = f4 >> 5, j4 = f4 & 31;
            float4 v = *reinterpret_cast<const float4*>(sp + o * 256 + p * 128 + j4 * 4);
            lds[j4 * 4 + 0][o] = v.x; lds[j4 * 4 + 1][o] = v.y;
            lds[j4 * 4 + 2][o] = v.z; lds[j4 * 4 + 3][o] = v.w;
        }
        __syncthreads();
        const int o = tid & 63, mq = tid >> 6;
#pragma unroll
        for (int r = 0; r < 32; ++r) {
            int lm = r * 4 + mq;
            int mky = p * 128 + lm;
            int mm = mky >> 4, ky = mky & 15;
            dst[((((size_t)(kxoff + mm)) * 16 + ky) * 64 + i) * 64 + o] = lds[lm][o];
        }
    }
}

// trig table for E: ttab[w][kk] bf16, kk=2*ky+c: c==0 -> cos(2pi ky w/256), c==1 -> -sin
__global__ __launch_bounds__(256) void ktrig(unsigned short* __restrict__ ttab) {
    int idx = blockIdx.x * 256 + threadIdx.x;    // 8192 = 256 w x 32 kk
    int w = idx >> 5, kk = idx & 31, ky = kk >> 1;
    int mm = (ky * w) & 255;
    float s, c;
    sincosf((float)mm * TWOPI_256, &s, &c);
    ttab[idx] = f2bf((kk & 1) ? -s : c);
}

// ---------------- Kernel C: channel mixing -> Y2[b][o][ky][kxi] --------------
__global__ __launch_bounds__(256) void kc_mix(const float* __restrict__ Xr,
                                              const float* __restrict__ Xi,
                                              const float* __restrict__ Wtr,
                                              const float* __restrict__ Wti,
                                              float* __restrict__ Yr,
                                              float* __restrict__ Yi) {
    __shared__ float xsr[512], xsi[512];
    const int tid = threadIdx.x;
    const int mode = blockIdx.x;
#pragma unroll
    for (int r = 0; r < 2; ++r) {
        int bi = r * 256 + tid;
        xsr[bi] = Xr[(size_t)bi * 512 + mode];
        xsi[bi] = Xi[(size_t)bi * 512 + mode];
    }
    __syncthreads();
    const int o = tid & 63, bg = tid >> 6;
    float yr0 = 0.f, yi0 = 0.f, yr1 = 0.f, yi1 = 0.f;
    const float* wrp = Wtr + (size_t)mode * 4096;
    const float* wip = Wti + (size_t)mode * 4096;
#pragma unroll 8
    for (int i = 0; i < 64; ++i) {
        float wr = wrp[i * 64 + o], wi = wip[i * 64 + o];
        float xr = xsr[bg * 64 + i],        xi = xsi[bg * 64 + i];
        yr0 += xr * wr - xi * wi;  yi0 += xr * wi + xi * wr;
        float xr2 = xsr[(bg + 4) * 64 + i], xi2 = xsi[(bg + 4) * 64 + i];
        yr1 += xr2 * wr - xi2 * wi;  yi1 += xr2 * wi + xi2 * wr;
    }
    const int kxi = mode >> 4, kym = mode & 15;
    const size_t e0 = ((size_t)bg * 64 + o) * 512 + kym * 32 + kxi;
    const size_t e1 = ((size_t)(bg + 4) * 64 + o) * 512 + kym * 32 + kxi;
    Yr[e0] = yr0;  Yi[e0] = yi0;
    Yr[e1] = yr1;  Yi[e1] = yi1;
}

// ---------------- Kernel D (MFMA): Y2 -> Z[b][o][h][ky] ----------------
// grid 256 = b(8) x og(16) x ri(2). block 256 (4 waves, wave = 64-h chunk).
// Per block: Z_ri[64 m=(ol,ky)][256 h] = A[64][64 k=(kxi,p)] . TD[ri][k][h]
// prescale sc(ky) folded into bf16 A. Output transposed via LDS -> coalesced.
__global__ __launch_bounds__(256) void kd_mfma(const float* __restrict__ Yr2,
                                               const float* __restrict__ Yi2,
                                               const unsigned short* __restrict__ tD,
                                               float* __restrict__ Zr,
                                               float* __restrict__ Zi) {
    __shared__ __align__(16) unsigned short at[4096];   // 8 KB: A[64 rows][64 k] swz
    __shared__ __align__(16) float zt[4][64][68];       // 68 KB: [wave][h][m] + pad
    const int tid = threadIdx.x;
    const int bid = blockIdx.x;
    const int b  = bid >> 5;
    const int og = (bid >> 1) & 15;
    const int ri = bid & 1;

    // ---- stage A: row = ol*16+ky, word j=kxi holds (Yr*sc, Yi*sc) bf16 ----
    {
        const int row = tid >> 2, q = tid & 3;
        const int ol = row >> 4, ky = row & 15;
        const float sc = (ky == 0) ? INV256 : 2.f * INV256;
        const size_t yb = ((size_t)(b * 64 + og * 4 + ol)) * 512 + ky * 32 + q * 8;
        f32x4 r0 = *reinterpret_cast<const f32x4*>(Yr2 + yb);
        f32x4 r1 = *reinterpret_cast<const f32x4*>(Yr2 + yb + 4);
        f32x4 i0 = *reinterpret_cast<const f32x4*>(Yi2 + yb);
        f32x4 i1 = *reinterpret_cast<const f32x4*>(Yi2 + yb + 4);
        unsigned wbuf[8];
#pragma unroll
        for (int t = 0; t < 4; ++t) {
            wbuf[t]     = (unsigned)f2bf(r0[t] * sc) | ((unsigned)f2bf(i0[t] * sc) << 16);
            wbuf[4 + t] = (unsigned)f2bf(r1[t] * sc) | ((unsigned)f2bf(i1[t] * sc) << 16);
        }
        char* base = reinterpret_cast<char*>(at) + row * 128;
        *reinterpret_cast<uint4*>(base + (((2 * q)     ^ (row & 7)) << 4)) = *reinterpret_cast<uint4*>(&wbuf[0]);
        *reinterpret_cast<uint4*>(base + (((2 * q + 1) ^ (row & 7)) << 4)) = *reinterpret_cast<uint4*>(&wbuf[4]);
    }
    __syncthreads();

    const int m = tid & 15, g = (tid >> 4) & 3, wid = tid >> 6;
    const int h0 = wid * 64;
    const unsigned short* td = tD + ri * 16384;

    f32x4 acc[4][4];
#pragma unroll
    for (int mf = 0; mf < 4; ++mf)
#pragma unroll
        for (int f = 0; f < 4; ++f)
#pragma unroll
            for (int r = 0; r < 4; ++r) acc[mf][f][r] = 0.f;

#pragma unroll
    for (int ks = 0; ks < 2; ++ks) {
        s16x8 af[4];
#pragma unroll
        for (int mf = 0; mf < 4; ++mf)
            af[mf] = *reinterpret_cast<const s16x8*>(
                reinterpret_cast<const char*>(at) + (mf * 16 + m) * 128
                + (((4 * ks + g) ^ (m & 7)) << 4));
#pragma unroll
        for (int f = 0; f < 4; ++f) {
            s16x8 bf = *reinterpret_cast<const s16x8*>(td + (h0 + f * 16 + m) * 64 + ks * 32 + 8 * g);
#pragma unroll
            for (int mf = 0; mf < 4; ++mf)
                acc[mf][f] = __builtin_amdgcn_mfma_f32_16x16x32_bf16(af[mf], bf, acc[mf][f], 0, 0, 0);
        }
    }

    // ---- transpose via LDS: zt[wave][h_local][m=(ol,ky)] ----
#pragma unroll
    for (int mf = 0; mf < 4; ++mf)
#pragma unroll
        for (int f = 0; f < 4; ++f)
#pragma unroll
            for (int r = 0; r < 4; ++r)
                zt[wid][f * 16 + m][mf * 16 + 4 * g + r] = acc[mf][f][r];
    __syncthreads();

    // ---- coalesced store: per (ol,hq): 64 lanes = 16 h x 4 ky-groups, f32x4 ----
    float* Zd = ri ? Zi : Zr;
    const int l = tid & 63;
    const int hloc = l >> 2, kg = l & 3;
#pragma unroll
    for (int ol = 0; ol < 4; ++ol)
#pragma unroll
        for (int hq = 0; hq < 4; ++hq) {
            f32x4 v = *reinterpret_cast<const f32x4*>(&zt[wid][hq * 16 + hloc][ol * 16 + 4 * kg]);
            size_t off = (((size_t)(b * 64 + og * 4 + ol)) * 256 + h0 + hq * 16 + hloc) * 16 + 4 * kg;
            *reinterpret_cast<f32x4*>(Zd + off) = v;
        }
}

// ---------------- Kernel E (MFMA): out = [cw|Z'] @ [x;trig] + bias ----------
__global__ __launch_bounds__(512) void ke_mfma(const float* __restrict__ x,
                                               const float* __restrict__ Zr,
                                               const float* __restrict__ Zi,
                                               const float* __restrict__ cw,
                                               const float* __restrict__ bias,
                                               const unsigned short* __restrict__ ttab,
                                               float* __restrict__ out) {
    __shared__ unsigned int bsx[8192];   // 32 KB: [w=256][16 words], swizzled
    const int tid = threadIdx.x;
    const int b = blockIdx.x >> 8;
    const int h = blockIdx.x & 255;

    const size_t xbase = ((size_t)b * 64) * 65536 + (size_t)h * 256;
    const int w0s = (tid & 63) * 4;
    float4 va[4], vb[4];
#pragma unroll
    for (int it = 0; it < 4; ++it) {
        int ip = it * 8 + (tid >> 6);
        va[it] = *reinterpret_cast<const float4*>(x + xbase + (size_t)(2 * ip) * 65536 + w0s);
        vb[it] = *reinterpret_cast<const float4*>(x + xbase + (size_t)(2 * ip + 1) * 65536 + w0s);
    }

    const int m = tid & 15;
    const int g = (tid >> 4) & 3;
    const int wave = tid >> 6;
    const int o0 = (wave >> 1) * 16;
    const int f0 = (wave & 1) * 8;
    const int o = o0 + m;

    s16x8 a0, a1, az;
    {
        f32x4 p  = *reinterpret_cast<const f32x4*>(cw + o * 64 + 8 * g);
        f32x4 q  = *reinterpret_cast<const f32x4*>(cw + o * 64 + 8 * g + 4);
        f32x4 p2 = *reinterpret_cast<const f32x4*>(cw + o * 64 + 32 + 8 * g);
        f32x4 q2 = *reinterpret_cast<const f32x4*>(cw + o * 64 + 32 + 8 * g + 4);
        size_t zoff = (((size_t)b * 64 + o) * 256 + h) * 16 + 4 * g;
        f32x4 zr = *reinterpret_cast<const f32x4*>(Zr + zoff);
        f32x4 zi = *reinterpret_cast<const f32x4*>(Zi + zoff);
#pragma unroll
        for (int t = 0; t < 4; ++t) {
            a0[t]     = (short)f2bf(p[t]);  a0[t + 4] = (short)f2bf(q[t]);
            a1[t]     = (short)f2bf(p2[t]); a1[t + 4] = (short)f2bf(q2[t]);
            az[2 * t]     = (short)f2bf(zr[t]);
            az[2 * t + 1] = (short)f2bf(zi[t]);
        }
    }
    s16x8 btr[8];
#pragma unroll
    for (int f = 0; f < 8; ++f) {
        int w = (f0 + f) * 16 + m;
        btr[f] = *reinterpret_cast<const s16x8*>(ttab + w * 32 + 8 * g);
    }
    f32x4 bv = *reinterpret_cast<const f32x4*>(bias + o0 + 4 * g);

#pragma unroll
    for (int it = 0; it < 4; ++it) {
        int ip = it * 8 + (tid >> 6);
        const float* pa = reinterpret_cast<const float*>(&va[it]);
        const float* pb = reinterpret_cast<const float*>(&vb[it]);
#pragma unroll
        for (int j = 0; j < 4; ++j) {
            int w = w0s + j;
            int c = (w ^ (w >> 3)) & 7;
            unsigned pk = (unsigned)f2bf(pa[j]) | ((unsigned)f2bf(pb[j]) << 16);
            bsx[(w << 5) + ((((ip >> 2) ^ c) << 2) | (ip & 3))] = pk;
        }
    }
    __syncthreads();

    f32x4 acc[8];
#pragma unroll
    for (int f = 0; f < 8; ++f)
#pragma unroll
        for (int r = 0; r < 4; ++r) acc[f][r] = 0.f;

#pragma unroll
    for (int f = 0; f < 8; ++f) {
        int w = (f0 + f) * 16 + m;
        int c = (w ^ (w >> 3)) & 7;
        const char* rb = reinterpret_cast<const char*>(bsx) + (w << 7);
        s16x8 bx0 = *reinterpret_cast<const s16x8*>(rb + ((g ^ c) << 4));
        s16x8 bx1 = *reinterpret_cast<const s16x8*>(rb + (((4 + g) ^ c) << 4));
        acc[f] = __builtin_amdgcn_mfma_f32_16x16x32_bf16(a0, bx0, acc[f], 0, 0, 0);
        acc[f] = __builtin_amdgcn_mfma_f32_16x16x32_bf16(a1, bx1, acc[f], 0, 0, 0);
        acc[f] = __builtin_amdgcn_mfma_f32_16x16x32_bf16(az, btr[f], acc[f], 0, 0, 0);
    }

    float* ob = out + ((size_t)b * 64 + o0 + 4 * g) * 65536 + (size_t)h * 256;
#pragma unroll
    for (int f = 0; f < 8; ++f) {
        int wb = (f0 + f) * 16 + m;
#pragma unroll
        for (int r = 0; r < 4; ++r)
            ob[(size_t)r * 65536 + wb] = acc[f][r] + bv[r];
    }
}

extern "C" void kernel_launch(void* const* d_in, const int* in_sizes, int n_in,
                              void* d_out, int out_size, void* d_ws, size_t ws_size,
                              hipStream_t stream) {
    const float* x   = (const float*)d_in[0];
    const float* w1r = (const float*)d_in[1];
    const float* w1i = (const float*)d_in[2];
    const float* w2r = (const float*)d_in[3];
    const float* w2i = (const float*)d_in[4];
    const float* cw  = (const float*)d_in[5];
    const float* cb  = (const float*)d_in[6];
    float* out = (float*)d_out;
    float* ws  = (float*)d_ws;
    unsigned short* tA   = (unsigned short*)(ws + O_TA);
    unsigned short* tB   = (unsigned short*)(ws + O_TB);
    unsigned short* ttab = (unsigned short*)(ws + O_TT);
    unsigned short* tD   = (unsigned short*)(ws + O_TD);

    ktabs<<<288, 256, 0, stream>>>(tA, tB, tD);
    ktrig<<<32, 256, 0, stream>>>(ttab);
    kw_prep<<<256, 256, 0, stream>>>(w1r, w1i, w2r, w2i, ws + O_WTR, ws + O_WTI);
    kab_fwd<<<512, 256, 0, stream>>>(x, tA, tB, ws + O_XR, ws + O_XI);
    kc_mix<<<512, 256, 0, stream>>>(ws + O_XR, ws + O_XI, ws + O_WTR, ws + O_WTI,
                                    ws + O_YR, ws + O_YI);
    kd_mfma<<<256, 256, 0, stream>>>(ws + O_YR, ws + O_YI, tD, ws + O_ZR, ws + O_ZI);
    ke_mfma<<<2048, 512, 0, stream>>>(x, ws + O_ZR, ws + O_ZI, cw, cb, ttab, out);
}

// Round 9
// 133.119 us; speedup vs baseline: 1.8016x; 1.1067x over previous
//
#include <hip/hip_runtime.h>
#include <math.h>

// FourierLayer: B=8, C=64, H=256, W=256, M1=M2=16.
// Pipeline:
//   AB (fused MFMA): per bc: phase1 U[32][256h] = TA . x^T ; phase2 X[64][16ky] = TB . U2
//   Wprep: Wt[kxi][ky][i][o] = (kxi<16 ? w1 : w2)[i][o][kxi&15][ky]
//   C: Y2[b][o][ky][kxi] = sum_i X[b][i][kxi][ky] * Wt[kxi][ky][i][o]  (complex, f32)
//   D (MFMA): Z[b][o][h][ky] = sum_kxi sc(ky)*(Yr,Yi).(trig) ; h-quartered for occupancy
//   E (MFMA): out[64o][128w-half] = [cw | Z] (64x96 bf16) @ [x ; trig] + bias

#define TWOPI_256 0.024543692606170259f   // 2*pi/256
#define INV256    0.00390625f

// ---------------- workspace layout (floats) ----------------
#define NX   262144             // 8*64*32*16
#define NWT  2097152            // 32*16*64*64
#define NZ   2097152            // 8*64*256*16
#define O_TA  0                 // 8192 ushort  (32x256 bf16)
#define O_TB  4096              // 32768 ushort (64x512 bf16)
#define O_XR  20480
#define O_XI  (O_XR + NX)
#define O_WTR (O_XI + NX)
#define O_WTI (O_WTR + NWT)
#define O_YR  (O_WTI + NWT)
#define O_YI  (O_YR + NX)
#define O_ZR  (O_YI + NX)
#define O_ZI  (O_ZR + NZ)
#define O_TT  (O_ZI + NZ)       // E trig table: 8192 ushort
#define O_TD  (O_TT + 4096)     // D trig table: 32768 ushort ([2 ri][256 h][64 k])

using s16x8 = __attribute__((ext_vector_type(8))) short;   // 8 bf16 (4 VGPRs)
using f32x4 = __attribute__((ext_vector_type(4))) float;   // MFMA acc

__device__ __forceinline__ unsigned short f2bf(float f) {  // RNE f32->bf16
    union { float f; unsigned u; } a; a.f = f;
    unsigned r = (a.u + 0x7fffu + ((a.u >> 16) & 1u)) >> 16;
    return (unsigned short)r;
}

// ---------------- table gen: TA (AB ph1) + TB (AB ph2) + TD (D) ----------------
__global__ __launch_bounds__(256) void ktabs(unsigned short* __restrict__ tA,
                                             unsigned short* __restrict__ tB,
                                             unsigned short* __restrict__ tD) {
    int idx = blockIdx.x * 256 + threadIdx.x;     // 73728 total
    if (idx < 8192) {
        // TA[col][w]: col<16 -> cos(2pi col w/256)/256 ; col>=16 -> -sin(...)/256
        int col = idx >> 8, w = idx & 255;
        int ky = col & 15;
        int mm = (ky * w) & 255;
        float s, c; sincosf((float)mm * TWOPI_256, &s, &c);
        tA[idx] = f2bf(col < 16 ? c * INV256 : -s * INV256);
    } else if (idx < 40960) {
        // TB[kx2][2h+p]: kx2<32 (Re rows): p0=cos, p1=sin ; kx2>=32 (Im): p0=-sin, p1=cos
        int j = idx - 8192;
        int kx2 = j >> 9, k = j & 511, h = k >> 1, p = k & 1;
        int kxi = kx2 & 31;
        int kx = (kxi < 16) ? kxi : (224 + kxi);
        int mm = (kx * h) & 255;
        float s, c; sincosf((float)mm * TWOPI_256, &s, &c);
        float v;
        if (kx2 < 32) v = p ? s : c;
        else          v = p ? c : -s;
        tB[j] = f2bf(v);
    } else {
        // TD[ri][h][k=2kxi+p], e^{+2pi i kx h/256}:
        //   ri=0 (Zr): p0 = cos, p1 = -sin ; ri=1 (Zi): p0 = sin, p1 = cos
        int j = idx - 40960;
        int ri = j >> 14, rem = j & 16383;
        int h = rem >> 6, k = rem & 63, kxi = k >> 1, p = k & 1;
        int kx = (kxi < 16) ? kxi : (224 + kxi);
        int mm = (kx * h) & 255;
        float s, c; sincosf((float)mm * TWOPI_256, &s, &c);
        float v;
        if (ri == 0) v = p ? -s : c;
        else         v = p ? c : s;
        tD[j] = f2bf(v);
    }
}

// ---------------- Kernel AB (fused MFMA): x -> X ----------------
// grid 512 (bc), block 256 (4 waves). Staging double-buffered in registers:
// chunk ch+1's 16 float4 issued before chunk ch is converted (T14 issue-early).
__global__ __launch_bounds__(256, 2) void kab_fwd(const float* __restrict__ x,
                                                  const unsigned short* __restrict__ tA,
                                                  const unsigned short* __restrict__ tB,
                                                  float* __restrict__ Xr,
                                                  float* __restrict__ Xi) {
    __shared__ __align__(16) unsigned short xt[16384];  // 32 KB [256h][64w] bf16 swz
    __shared__ __align__(16) unsigned int   ub[4096];   // 16 KB U2 [16ky][512k] swz
    const int tid  = threadIdx.x;
    const int bc   = blockIdx.x;
    const int m    = tid & 15;
    const int g    = (tid >> 4) & 3;
    const int wave = tid >> 6;

    const float* xp = x + (size_t)bc * 65536;
    const int hh = tid >> 4;        // 0..15: h offset within 16-row group
    const int w4 = tid & 15;        // float4 index along w

    f32x4 acc[2][4];
#pragma unroll
    for (int a = 0; a < 2; ++a)
#pragma unroll
        for (int fn = 0; fn < 4; ++fn)
#pragma unroll
            for (int r = 0; r < 4; ++r) acc[a][fn][r] = 0.f;

    float4 stg[2][16];
#pragma unroll
    for (int it = 0; it < 16; ++it)
        stg[0][it] = *reinterpret_cast<const float4*>(xp + (it * 16 + hh) * 256 + w4 * 4);

#pragma unroll
    for (int ch = 0; ch < 4; ++ch) {
        const int cur = ch & 1;
        // issue next chunk's loads before consuming current (latency hiding)
        if (ch < 3) {
#pragma unroll
            for (int it = 0; it < 16; ++it)
                stg[cur ^ 1][it] = *reinterpret_cast<const float4*>(
                    xp + (it * 16 + hh) * 256 + (ch + 1) * 64 + w4 * 4);
        }
        // convert current chunk -> LDS (16B-block XOR swizzle by h&7)
#pragma unroll
        for (int it = 0; it < 16; ++it) {
            int h = it * 16 + hh;
            float4 v = stg[cur][it];
            unsigned lo = (unsigned)f2bf(v.x) | ((unsigned)f2bf(v.y) << 16);
            unsigned hi = (unsigned)f2bf(v.z) | ((unsigned)f2bf(v.w) << 16);
            int wl  = w4 * 4;
            int blk = (wl >> 3) ^ (h & 7);
            char* p = reinterpret_cast<char*>(xt) + (h << 7) + (blk << 4) + ((wl & 7) << 1);
            *reinterpret_cast<uint2*>(p) = make_uint2(lo, hi);
        }
        __syncthreads();
#pragma unroll
        for (int ks = 0; ks < 2; ++ks) {
            s16x8 a0 = *reinterpret_cast<const s16x8*>(tA + m * 256        + ch * 64 + ks * 32 + 8 * g);
            s16x8 a1 = *reinterpret_cast<const s16x8*>(tA + (16 + m) * 256 + ch * 64 + ks * 32 + 8 * g);
#pragma unroll
            for (int fn = 0; fn < 4; ++fn) {
                int h   = wave * 64 + fn * 16 + m;
                int blk = (4 * ks + g) ^ (h & 7);
                s16x8 bf = *reinterpret_cast<const s16x8*>(
                    reinterpret_cast<const char*>(xt) + (h << 7) + (blk << 4));
                acc[0][fn] = __builtin_amdgcn_mfma_f32_16x16x32_bf16(a0, bf, acc[0][fn], 0, 0, 0);
                acc[1][fn] = __builtin_amdgcn_mfma_f32_16x16x32_bf16(a1, bf, acc[1][fn], 0, 0, 0);
            }
        }
        __syncthreads();
    }

#pragma unroll
    for (int fn = 0; fn < 4; ++fn) {
        int h = wave * 64 + fn * 16 + m;
#pragma unroll
        for (int r = 0; r < 4; ++r) {
            int ky = 4 * g + r;
            unsigned pk = (unsigned)f2bf(acc[0][fn][r]) | ((unsigned)f2bf(acc[1][fn][r]) << 16);
            int blk = (h >> 2) ^ (ky & 7);
            ub[ky * 256 + blk * 4 + (h & 3)] = pk;
        }
    }
    __syncthreads();

    f32x4 acc2;
#pragma unroll
    for (int r = 0; r < 4; ++r) acc2[r] = 0.f;
#pragma unroll
    for (int ks = 0; ks < 16; ++ks) {
        s16x8 a2 = *reinterpret_cast<const s16x8*>(tB + (wave * 16 + m) * 512 + ks * 32 + 8 * g);
        int blk = (4 * ks + g) ^ (m & 7);
        s16x8 b2 = *reinterpret_cast<const s16x8*>(
            reinterpret_cast<const char*>(ub) + m * 1024 + (blk << 4));
        acc2 = __builtin_amdgcn_mfma_f32_16x16x32_bf16(a2, b2, acc2, 0, 0, 0);
    }
#pragma unroll
    for (int r = 0; r < 4; ++r) {
        int kx2 = wave * 16 + 4 * g + r;
        if (kx2 < 32) Xr[(size_t)bc * 512 + kx2 * 16 + m]        = acc2[r];
        else          Xi[(size_t)bc * 512 + (kx2 - 32) * 16 + m] = acc2[r];
    }
}

// ---------------- Kernel Wprep: weight transpose --------------
__global__ __launch_bounds__(256) void kw_prep(const float* __restrict__ w1r,
                                               const float* __restrict__ w1i,
                                               const float* __restrict__ w2r,
                                               const float* __restrict__ w2i,
                                               float* __restrict__ Wtr,
                                               float* __restrict__ Wti) {
    __shared__ float lds[128][65];
    const int tid = threadIdx.x;
    const int a = blockIdx.x >> 6;
    const int i = blockIdx.x & 63;
    const float* src = (a == 0) ? w1r : (a == 1) ? w1i : (a == 2) ? w2r : w2i;
    float* dst = (a & 1) ? Wti : Wtr;
    const int kxoff = (a >> 1) << 4;
    const float* sp = src + (size_t)i * 16384;

    for (int p = 0; p < 2; ++p) {
        if (p) __syncthreads();
#pragma unroll
        for (int it = 0; it < 8; ++it) {
            int f4 = it * 256 + tid;
            int o = f4 >> 5, j4 = f4 & 31;
            float4 v = *reinterpret_cast<const float4*>(sp + o * 256 + p * 128 + j4 * 4);
            lds[j4 * 4 + 0][o] = v.x; lds[j4 * 4 + 1][o] = v.y;
            lds[j4 * 4 + 2][o] = v.z; lds[j4 * 4 + 3][o] = v.w;
        }
        __syncthreads();
        const int o = tid & 63, mq = tid >> 6;
#pragma unroll
        for (int r = 0; r < 32; ++r) {
            int lm = r * 4 + mq;
            int mky = p * 128 + lm;
            int mm = mky >> 4, ky = mky & 15;
            dst[((((size_t)(kxoff + mm)) * 16 + ky) * 64 + i) * 64 + o] = lds[lm][o];
        }
    }
}

// trig table for E: ttab[w][kk] bf16, kk=2*ky+c: c==0 -> cos(2pi ky w/256), c==1 -> -sin
__global__ __launch_bounds__(256) void ktrig(unsigned short* __restrict__ ttab) {
    int idx = blockIdx.x * 256 + threadIdx.x;    // 8192 = 256 w x 32 kk
    int w = idx >> 5, kk = idx & 31, ky = kk >> 1;
    int mm = (ky * w) & 255;
    float s, c;
    sincosf((float)mm * TWOPI_256, &s, &c);
    ttab[idx] = f2bf((kk & 1) ? -s : c);
}

// ---------------- Kernel C: channel mixing -> Y2[b][o][ky][kxi] --------------
__global__ __launch_bounds__(256) void kc_mix(const float* __restrict__ Xr,
                                              const float* __restrict__ Xi,
                                              const float* __restrict__ Wtr,
                                              const float* __restrict__ Wti,
                                              float* __restrict__ Yr,
                                              float* __restrict__ Yi) {
    __shared__ float xsr[512], xsi[512];
    const int tid = threadIdx.x;
    const int mode = blockIdx.x;
#pragma unroll
    for (int r = 0; r < 2; ++r) {
        int bi = r * 256 + tid;
        xsr[bi] = Xr[(size_t)bi * 512 + mode];
        xsi[bi] = Xi[(size_t)bi * 512 + mode];
    }
    __syncthreads();
    const int o = tid & 63, bg = tid >> 6;
    float yr0 = 0.f, yi0 = 0.f, yr1 = 0.f, yi1 = 0.f;
    const float* wrp = Wtr + (size_t)mode * 4096;
    const float* wip = Wti + (size_t)mode * 4096;
#pragma unroll 8
    for (int i = 0; i < 64; ++i) {
        float wr = wrp[i * 64 + o], wi = wip[i * 64 + o];
        float xr = xsr[bg * 64 + i],        xi = xsi[bg * 64 + i];
        yr0 += xr * wr - xi * wi;  yi0 += xr * wi + xi * wr;
        float xr2 = xsr[(bg + 4) * 64 + i], xi2 = xsi[(bg + 4) * 64 + i];
        yr1 += xr2 * wr - xi2 * wi;  yi1 += xr2 * wi + xi2 * wr;
    }
    const int kxi = mode >> 4, kym = mode & 15;
    const size_t e0 = ((size_t)bg * 64 + o) * 512 + kym * 32 + kxi;
    const size_t e1 = ((size_t)(bg + 4) * 64 + o) * 512 + kym * 32 + kxi;
    Yr[e0] = yr0;  Yi[e0] = yi0;
    Yr[e1] = yr1;  Yi[e1] = yi1;
}

// ---------------- Kernel D (MFMA): Y2 -> Z[b][o][h][ky] ----------------
// grid 1024 = b(8) x og(16) x ri(2) x hs(4). block 256 (4 waves, wave = 16-h frag).
// Per block: Z_ri[64 m=(ol,ky)][64 h] = A[64][64 k=(kxi,p)] . TD[ri][k][h-slice]
__global__ __launch_bounds__(256) void kd_mfma(const float* __restrict__ Yr2,
                                               const float* __restrict__ Yi2,
                                               const unsigned short* __restrict__ tD,
                                               float* __restrict__ Zr,
                                               float* __restrict__ Zi) {
    __shared__ __align__(16) unsigned short at[4096];   // 8 KB: A[64 rows][64 k] swz
    __shared__ __align__(16) float zt[64][68];          // 17.4 KB: [h_local][m] + pad
    const int tid = threadIdx.x;
    const int bid = blockIdx.x;
    const int b  = bid >> 7;
    const int og = (bid >> 3) & 15;
    const int ri = (bid >> 2) & 1;
    const int hs = bid & 3;

    // ---- stage A: row = ol*16+ky, word j=kxi holds (Yr*sc, Yi*sc) bf16 ----
    {
        const int row = tid >> 2, q = tid & 3;
        const int ol = row >> 4, ky = row & 15;
        const float sc = (ky == 0) ? INV256 : 2.f * INV256;
        const size_t yb = ((size_t)(b * 64 + og * 4 + ol)) * 512 + ky * 32 + q * 8;
        f32x4 r0 = *reinterpret_cast<const f32x4*>(Yr2 + yb);
        f32x4 r1 = *reinterpret_cast<const f32x4*>(Yr2 + yb + 4);
        f32x4 i0 = *reinterpret_cast<const f32x4*>(Yi2 + yb);
        f32x4 i1 = *reinterpret_cast<const f32x4*>(Yi2 + yb + 4);
        unsigned wbuf[8];
#pragma unroll
        for (int t = 0; t < 4; ++t) {
            wbuf[t]     = (unsigned)f2bf(r0[t] * sc) | ((unsigned)f2bf(i0[t] * sc) << 16);
            wbuf[4 + t] = (unsigned)f2bf(r1[t] * sc) | ((unsigned)f2bf(i1[t] * sc) << 16);
        }
        char* base = reinterpret_cast<char*>(at) + row * 128;
        *reinterpret_cast<uint4*>(base + (((2 * q)     ^ (row & 7)) << 4)) = *reinterpret_cast<uint4*>(&wbuf[0]);
        *reinterpret_cast<uint4*>(base + (((2 * q + 1) ^ (row & 7)) << 4)) = *reinterpret_cast<uint4*>(&wbuf[4]);
    }
    __syncthreads();

    const int m = tid & 15, g = (tid >> 4) & 3, wid = tid >> 6;
    const unsigned short* td = tD + ri * 16384;
    const int hg = hs * 64 + wid * 16 + m;     // global h of this lane's B-row

    f32x4 acc[4];
#pragma unroll
    for (int mf = 0; mf < 4; ++mf)
#pragma unroll
        for (int r = 0; r < 4; ++r) acc[mf][r] = 0.f;

#pragma unroll
    for (int ks = 0; ks < 2; ++ks) {
        s16x8 bf = *reinterpret_cast<const s16x8*>(td + hg * 64 + ks * 32 + 8 * g);
#pragma unroll
        for (int mf = 0; mf < 4; ++mf) {
            s16x8 af = *reinterpret_cast<const s16x8*>(
                reinterpret_cast<const char*>(at) + (mf * 16 + m) * 128
                + (((4 * ks + g) ^ (m & 7)) << 4));
            acc[mf] = __builtin_amdgcn_mfma_f32_16x16x32_bf16(af, bf, acc[mf], 0, 0, 0);
        }
    }

    // ---- transpose via LDS: zt[h_local][m=(ol,ky)] ----
#pragma unroll
    for (int mf = 0; mf < 4; ++mf)
#pragma unroll
        for (int r = 0; r < 4; ++r)
            zt[wid * 16 + m][mf * 16 + 4 * g + r] = acc[mf][r];
    __syncthreads();

    // ---- coalesced store: 4 KB contiguous per (ol,hq) across the block ----
    float* Zd = ri ? Zi : Zr;
    const int ol = tid >> 6, hloc = (tid >> 2) & 15, kg = tid & 3;
#pragma unroll
    for (int hq = 0; hq < 4; ++hq) {
        f32x4 v = *reinterpret_cast<const f32x4*>(&zt[hq * 16 + hloc][ol * 16 + 4 * kg]);
        size_t off = (((size_t)(b * 64 + og * 4 + ol)) * 256 + hs * 64 + hq * 16 + hloc) * 16 + 4 * kg;
        *reinterpret_cast<f32x4*>(Zd + off) = v;
    }
}

// ---------------- Kernel E (MFMA): out = [cw|Z] @ [x;trig] + bias ----------
// grid 4096 = (b, h, w-half). block 256 (4 waves; wave = 16-o group x 128 w).
__global__ __launch_bounds__(256) void ke_mfma(const float* __restrict__ x,
                                               const float* __restrict__ Zr,
                                               const float* __restrict__ Zi,
                                               const float* __restrict__ cw,
                                               const float* __restrict__ bias,
                                               const unsigned short* __restrict__ ttab,
                                               float* __restrict__ out) {
    __shared__ unsigned int bsx[4096];   // 16 KB: [128 w][32 words], swizzled
    const int tid = threadIdx.x;
    const int b  = blockIdx.x >> 9;
    const int h  = (blockIdx.x >> 1) & 255;
    const int wh = blockIdx.x & 1;
    const int wbase = wh * 128;

    const size_t xbase = ((size_t)b * 64) * 65536 + (size_t)h * 256 + wbase;
    const int wl4 = (tid & 31) * 4;      // float4 start along w (local)
    const int ipg = tid >> 5;            // 0..7: i-pair group
    float4 va[4], vb[4];
#pragma unroll
    for (int it = 0; it < 4; ++it) {
        int ip = it * 8 + ipg;
        va[it] = *reinterpret_cast<const float4*>(x + xbase + (size_t)(2 * ip) * 65536 + wl4);
        vb[it] = *reinterpret_cast<const float4*>(x + xbase + (size_t)(2 * ip + 1) * 65536 + wl4);
    }

    const int m = tid & 15;
    const int g = (tid >> 4) & 3;
    const int wave = tid >> 6;
    const int o = wave * 16 + m;

    s16x8 a0, a1, az;
    {
        f32x4 p  = *reinterpret_cast<const f32x4*>(cw + o * 64 + 8 * g);
        f32x4 q  = *reinterpret_cast<const f32x4*>(cw + o * 64 + 8 * g + 4);
        f32x4 p2 = *reinterpret_cast<const f32x4*>(cw + o * 64 + 32 + 8 * g);
        f32x4 q2 = *reinterpret_cast<const f32x4*>(cw + o * 64 + 32 + 8 * g + 4);
        size_t zoff = (((size_t)b * 64 + o) * 256 + h) * 16 + 4 * g;
        f32x4 zr = *reinterpret_cast<const f32x4*>(Zr + zoff);
        f32x4 zi = *reinterpret_cast<const f32x4*>(Zi + zoff);
#pragma unroll
        for (int t = 0; t < 4; ++t) {
            a0[t]     = (short)f2bf(p[t]);  a0[t + 4] = (short)f2bf(q[t]);
            a1[t]     = (short)f2bf(p2[t]); a1[t + 4] = (short)f2bf(q2[t]);
            az[2 * t]     = (short)f2bf(zr[t]);
            az[2 * t + 1] = (short)f2bf(zi[t]);
        }
    }
    s16x8 btr[8];
#pragma unroll
    for (int f = 0; f < 8; ++f) {
        int w = wbase + f * 16 + m;
        btr[f] = *reinterpret_cast<const s16x8*>(ttab + w * 32 + 8 * g);
    }
    f32x4 bv = *reinterpret_cast<const f32x4*>(bias + wave * 16 + 4 * g);

#pragma unroll
    for (int it = 0; it < 4; ++it) {
        int ip = it * 8 + ipg;
        const float* pa = reinterpret_cast<const float*>(&va[it]);
        const float* pb = reinterpret_cast<const float*>(&vb[it]);
#pragma unroll
        for (int j = 0; j < 4; ++j) {
            int wl = wl4 + j;
            int c = (wl ^ (wl >> 3)) & 7;
            unsigned pk = (unsigned)f2bf(pa[j]) | ((unsigned)f2bf(pb[j]) << 16);
            bsx[(wl << 5) + ((((ip >> 2) ^ c) << 2) | (ip & 3))] = pk;
        }
    }
    __syncthreads();

    f32x4 acc[8];
#pragma unroll
    for (int f = 0; f < 8; ++f)
#pragma unroll
        for (int r = 0; r < 4; ++r) acc[f][r] = 0.f;

#pragma unroll
    for (int f = 0; f < 8; ++f) {
        int wl = f * 16 + m;
        int c = (wl ^ (wl >> 3)) & 7;
        const char* rb = reinterpret_cast<const char*>(bsx) + (wl << 7);
        s16x8 bx0 = *reinterpret_cast<const s16x8*>(rb + ((g ^ c) << 4));
        s16x8 bx1 = *reinterpret_cast<const s16x8*>(rb + (((4 + g) ^ c) << 4));
        acc[f] = __builtin_amdgcn_mfma_f32_16x16x32_bf16(a0, bx0, acc[f], 0, 0, 0);
        acc[f] = __builtin_amdgcn_mfma_f32_16x16x32_bf16(a1, bx1, acc[f], 0, 0, 0);
        acc[f] = __builtin_amdgcn_mfma_f32_16x16x32_bf16(az, btr[f], acc[f], 0, 0, 0);
    }

    float* ob = out + ((size_t)(b * 64 + wave * 16 + 4 * g)) * 65536 + (size_t)h * 256 + wbase;
#pragma unroll
    for (int f = 0; f < 8; ++f) {
#pragma unroll
        for (int r = 0; r < 4; ++r)
            ob[(size_t)r * 65536 + f * 16 + m] = acc[f][r] + bv[r];
    }
}

extern "C" void kernel_launch(void* const* d_in, const int* in_sizes, int n_in,
                              void* d_out, int out_size, void* d_ws, size_t ws_size,
                              hipStream_t stream) {
    const float* x   = (const float*)d_in[0];
    const float* w1r = (const float*)d_in[1];
    const float* w1i = (const float*)d_in[2];
    const float* w2r = (const float*)d_in[3];
    const float* w2i = (const float*)d_in[4];
    const float* cw  = (const float*)d_in[5];
    const float* cb  = (const float*)d_in[6];
    float* out = (float*)d_out;
    float* ws  = (float*)d_ws;
    unsigned short* tA   = (unsigned short*)(ws + O_TA);
    unsigned short* tB   = (unsigned short*)(ws + O_TB);
    unsigned short* ttab = (unsigned short*)(ws + O_TT);
    unsigned short* tD   = (unsigned short*)(ws + O_TD);

    ktabs<<<288, 256, 0, stream>>>(tA, tB, tD);
    ktrig<<<32, 256, 0, stream>>>(ttab);
    kw_prep<<<256, 256, 0, stream>>>(w1r, w1i, w2r, w2i, ws + O_WTR, ws + O_WTI);
    kab_fwd<<<512, 256, 0, stream>>>(x, tA, tB, ws + O_XR, ws + O_XI);
    kc_mix<<<512, 256, 0, stream>>>(ws + O_XR, ws + O_XI, ws + O_WTR, ws + O_WTI,
                                    ws + O_YR, ws + O_YI);
    kd_mfma<<<1024, 256, 0, stream>>>(ws + O_YR, ws + O_YI, tD, ws + O_ZR, ws + O_ZI);
    ke_mfma<<<4096, 256, 0, stream>>>(x, ws + O_ZR, ws + O_ZI, cw, cb, ttab, out);
}

// Round 11
// 127.520 us; speedup vs baseline: 1.8808x; 1.0439x over previous
//
#include <hip/hip_runtime.h>
#include <math.h>

// FourierLayer: B=8, C=64, H=256, W=256, M1=M2=16.
// Pipeline:
//   AB (fused MFMA): per bc: phase1 U[32][256h] = TA . x^T ; phase2 X[64][16ky] = TB . U2
//   Wprep: Wt[kxi][ky][i][o] = (kxi<16 ? w1 : w2)[i][o][kxi&15][ky]
//   C: Y2[b][o][ky][kxi] (i-split partials A/B) = sum_i X * Wt  (complex, f32)
//   D (MFMA): Z[b][o][h][ky] = sum_kxi sc(ky)*(YrA+YrB, YiA+YiB).(trig), h-quartered
//   E (MFMA): out[64o][128w-half] = [cw | Z] (64x96 bf16) @ [x ; trig] + bias
// All f32->bf16 pair-packs are pure-C round-half-up (bfpack); tables use RNE f2bf.

#define TWOPI_256 0.024543692606170259f   // 2*pi/256
#define INV256    0.00390625f

// ---------------- workspace layout (floats) ----------------
#define NX   262144             // 8*64*32*16  (also Y size 8*64*512)
#define NWT  2097152            // 32*16*64*64
#define NZ   2097152            // 8*64*256*16
#define O_TA  0                 // 8192 ushort  (32x256 bf16)
#define O_TB  4096              // 32768 ushort (64x512 bf16)
#define O_XR  20480
#define O_XI  (O_XR + NX)
#define O_WTR (O_XI + NX)
#define O_WTI (O_WTR + NWT)
#define O_YRA (O_WTI + NWT)
#define O_YIA (O_YRA + NX)
#define O_ZR  (O_YIA + NX)
#define O_ZI  (O_ZR + NZ)
#define O_TT  (O_ZI + NZ)       // E trig table: 8192 ushort
#define O_TD  (O_TT + 4096)     // D trig table: 32768 ushort ([2 ri][256 h][64 k])
#define O_YRB (O_TD + 16384)    // C partial half B
#define O_YIB (O_YRB + NX)
// end = O_YIB + NX ~= 10.0M floats ~= 38.2 MiB

using s16x8 = __attribute__((ext_vector_type(8))) short;   // 8 bf16 (4 VGPRs)
using f32x4 = __attribute__((ext_vector_type(4))) float;   // MFMA acc
using u32x4 = __attribute__((ext_vector_type(4))) unsigned;

__device__ __forceinline__ unsigned short f2bf(float f) {  // RNE f32->bf16 (table gen only)
    union { float f; unsigned u; } a; a.f = f;
    unsigned r = (a.u + 0x7fffu + ((a.u >> 16) & 1u)) >> 16;
    return (unsigned short)r;
}

// pure-C packed convert (round-half-up): lo16 = bf16(a), hi16 = bf16(b)
__device__ __forceinline__ unsigned bfpack(float a, float b) {
    union { float f; unsigned u; } x, y; x.f = a; y.f = b;
    return ((x.u + 0x8000u) >> 16) | ((y.u + 0x8000u) & 0xffff0000u);
}

// ---------------- table gen: TA + TB + TD + TT(E) ----------------
__global__ __launch_bounds__(256) void ktabs(unsigned short* __restrict__ tA,
                                             unsigned short* __restrict__ tB,
                                             unsigned short* __restrict__ tD,
                                             unsigned short* __restrict__ tT) {
    int idx = blockIdx.x * 256 + threadIdx.x;     // 81920 total
    if (idx < 8192) {
        // TA[col][w]: col<16 -> cos(2pi col w/256)/256 ; col>=16 -> -sin(...)/256
        int col = idx >> 8, w = idx & 255;
        int ky = col & 15;
        int mm = (ky * w) & 255;
        float s, c; sincosf((float)mm * TWOPI_256, &s, &c);
        tA[idx] = f2bf(col < 16 ? c * INV256 : -s * INV256);
    } else if (idx < 40960) {
        // TB[kx2][2h+p]: kx2<32 (Re): p0=cos, p1=sin ; kx2>=32 (Im): p0=-sin, p1=cos
        int j = idx - 8192;
        int kx2 = j >> 9, k = j & 511, h = k >> 1, p = k & 1;
        int kxi = kx2 & 31;
        int kx = (kxi < 16) ? kxi : (224 + kxi);
        int mm = (kx * h) & 255;
        float s, c; sincosf((float)mm * TWOPI_256, &s, &c);
        float v;
        if (kx2 < 32) v = p ? s : c;
        else          v = p ? c : -s;
        tB[j] = f2bf(v);
    } else if (idx < 73728) {
        // TD[ri][h][k=2kxi+p], e^{+2pi i kx h/256}:
        //   ri=0 (Zr): p0 = cos, p1 = -sin ; ri=1 (Zi): p0 = sin, p1 = cos
        int j = idx - 40960;
        int ri = j >> 14, rem = j & 16383;
        int h = rem >> 6, k = rem & 63, kxi = k >> 1, p = k & 1;
        int kx = (kxi < 16) ? kxi : (224 + kxi);
        int mm = (kx * h) & 255;
        float s, c; sincosf((float)mm * TWOPI_256, &s, &c);
        float v;
        if (ri == 0) v = p ? -s : c;
        else         v = p ? c : s;
        tD[j] = f2bf(v);
    } else {
        // TT[w][kk] for E: kk=2*ky+c: c==0 -> cos(2pi ky w/256), c==1 -> -sin
        int j = idx - 73728;
        int w = j >> 5, kk = j & 31, ky = kk >> 1;
        int mm = (ky * w) & 255;
        float s, c; sincosf((float)mm * TWOPI_256, &s, &c);
        tT[j] = f2bf((kk & 1) ? -s : c);
    }
}

// ---------------- Kernel AB (fused MFMA): x -> X ----------------
// grid 512 (bc), block 256 (4 waves). Register-double-buffered staging.
__global__ __launch_bounds__(256, 2) void kab_fwd(const float* __restrict__ x,
                                                  const unsigned short* __restrict__ tA,
                                                  const unsigned short* __restrict__ tB,
                                                  float* __restrict__ Xr,
                                                  float* __restrict__ Xi) {
    __shared__ __align__(16) unsigned short xt[16384];  // 32 KB [256h][64w] bf16 swz
    __shared__ __align__(16) unsigned int   ub[4096];   // 16 KB U2 [16ky][512k] swz
    const int tid  = threadIdx.x;
    const int bc   = blockIdx.x;
    const int m    = tid & 15;
    const int g    = (tid >> 4) & 3;
    const int wave = tid >> 6;

    const float* xp = x + (size_t)bc * 65536;
    const int hh = tid >> 4;        // 0..15: h offset within 16-row group
    const int w4 = tid & 15;        // float4 index along w

    f32x4 acc[2][4];
#pragma unroll
    for (int a = 0; a < 2; ++a)
#pragma unroll
        for (int fn = 0; fn < 4; ++fn)
#pragma unroll
            for (int r = 0; r < 4; ++r) acc[a][fn][r] = 0.f;

    float4 stg[2][16];
#pragma unroll
    for (int it = 0; it < 16; ++it)
        stg[0][it] = *reinterpret_cast<const float4*>(xp + (it * 16 + hh) * 256 + w4 * 4);

#pragma unroll
    for (int ch = 0; ch < 4; ++ch) {
        const int cur = ch & 1;
        if (ch < 3) {
#pragma unroll
            for (int it = 0; it < 16; ++it)
                stg[cur ^ 1][it] = *reinterpret_cast<const float4*>(
                    xp + (it * 16 + hh) * 256 + (ch + 1) * 64 + w4 * 4);
        }
#pragma unroll
        for (int it = 0; it < 16; ++it) {
            int h = it * 16 + hh;
            float4 v = stg[cur][it];
            unsigned lo = bfpack(v.x, v.y);
            unsigned hi = bfpack(v.z, v.w);
            int wl  = w4 * 4;
            int blk = (wl >> 3) ^ (h & 7);
            char* p = reinterpret_cast<char*>(xt) + (h << 7) + (blk << 4) + ((wl & 7) << 1);
            *reinterpret_cast<uint2*>(p) = make_uint2(lo, hi);
        }
        __syncthreads();
#pragma unroll
        for (int ks = 0; ks < 2; ++ks) {
            s16x8 a0 = *reinterpret_cast<const s16x8*>(tA + m * 256        + ch * 64 + ks * 32 + 8 * g);
            s16x8 a1 = *reinterpret_cast<const s16x8*>(tA + (16 + m) * 256 + ch * 64 + ks * 32 + 8 * g);
#pragma unroll
            for (int fn = 0; fn < 4; ++fn) {
                int h   = wave * 64 + fn * 16 + m;
                int blk = (4 * ks + g) ^ (h & 7);
                s16x8 bf = *reinterpret_cast<const s16x8*>(
                    reinterpret_cast<const char*>(xt) + (h << 7) + (blk << 4));
                acc[0][fn] = __builtin_amdgcn_mfma_f32_16x16x32_bf16(a0, bf, acc[0][fn], 0, 0, 0);
                acc[1][fn] = __builtin_amdgcn_mfma_f32_16x16x32_bf16(a1, bf, acc[1][fn], 0, 0, 0);
            }
        }
        __syncthreads();
    }

#pragma unroll
    for (int fn = 0; fn < 4; ++fn) {
        int h = wave * 64 + fn * 16 + m;
#pragma unroll
        for (int r = 0; r < 4; ++r) {
            int ky = 4 * g + r;
            unsigned pk = bfpack(acc[0][fn][r], acc[1][fn][r]);
            int blk = (h >> 2) ^ (ky & 7);
            ub[ky * 256 + blk * 4 + (h & 3)] = pk;
        }
    }
    __syncthreads();

    f32x4 acc2;
#pragma unroll
    for (int r = 0; r < 4; ++r) acc2[r] = 0.f;
#pragma unroll
    for (int ks = 0; ks < 16; ++ks) {
        s16x8 a2 = *reinterpret_cast<const s16x8*>(tB + (wave * 16 + m) * 512 + ks * 32 + 8 * g);
        int blk = (4 * ks + g) ^ (m & 7);
        s16x8 b2 = *reinterpret_cast<const s16x8*>(
            reinterpret_cast<const char*>(ub) + m * 1024 + (blk << 4));
        acc2 = __builtin_amdgcn_mfma_f32_16x16x32_bf16(a2, b2, acc2, 0, 0, 0);
    }
#pragma unroll
    for (int r = 0; r < 4; ++r) {
        int kx2 = wave * 16 + 4 * g + r;
        if (kx2 < 32) Xr[(size_t)bc * 512 + kx2 * 16 + m]        = acc2[r];
        else          Xi[(size_t)bc * 512 + (kx2 - 32) * 16 + m] = acc2[r];
    }
}

// ---------------- Kernel Wprep: weight transpose --------------
__global__ __launch_bounds__(256) void kw_prep(const float* __restrict__ w1r,
                                               const float* __restrict__ w1i,
                                               const float* __restrict__ w2r,
                                               const float* __restrict__ w2i,
                                               float* __restrict__ Wtr,
                                               float* __restrict__ Wti) {
    __shared__ float lds[128][65];
    const int tid = threadIdx.x;
    const int a = blockIdx.x >> 6;
    const int i = blockIdx.x & 63;
    const float* src = (a == 0) ? w1r : (a == 1) ? w1i : (a == 2) ? w2r : w2i;
    float* dst = (a & 1) ? Wti : Wtr;
    const int kxoff = (a >> 1) << 4;
    const float* sp = src + (size_t)i * 16384;

    for (int p = 0; p < 2; ++p) {
        if (p) __syncthreads();
#pragma unroll
        for (int it = 0; it < 8; ++it) {
            int f4 = it * 256 + tid;
            int o = f4 >> 5, j4 = f4 & 31;
            float4 v = *reinterpret_cast<const float4*>(sp + o * 256 + p * 128 + j4 * 4);
            lds[j4 * 4 + 0][o] = v.x; lds[j4 * 4 + 1][o] = v.y;
            lds[j4 * 4 + 2][o] = v.z; lds[j4 * 4 + 3][o] = v.w;
        }
        __syncthreads();
        const int o = tid & 63, mq = tid >> 6;
#pragma unroll
        for (int r = 0; r < 32; ++r) {
            int lm = r * 4 + mq;
            int mky = p * 128 + lm;
            int mm = mky >> 4, ky = mky & 15;
            dst[((((size_t)(kxoff + mm)) * 16 + ky) * 64 + i) * 64 + o] = lds[lm][o];
        }
    }
}

// ---------------- Kernel C: channel mixing (i-split) -> Y partial A/B --------
// grid 1024 = mode(512) x ih(2). Each block sums 32 i's.
__global__ __launch_bounds__(256) void kc_mix(const float* __restrict__ Xr,
                                              const float* __restrict__ Xi,
                                              const float* __restrict__ Wtr,
                                              const float* __restrict__ Wti,
                                              float* __restrict__ YrA,
                                              float* __restrict__ YiA,
                                              float* __restrict__ YrB,
                                              float* __restrict__ YiB) {
    __shared__ float xsr[256], xsi[256];
    const int tid  = threadIdx.x;
    const int mode = blockIdx.x >> 1;
    const int ih   = blockIdx.x & 1;
    {
        int b = tid >> 5, il = tid & 31;
        xsr[tid] = Xr[(size_t)(b * 64 + ih * 32 + il) * 512 + mode];
        xsi[tid] = Xi[(size_t)(b * 64 + ih * 32 + il) * 512 + mode];
    }
    __syncthreads();
    const int o = tid & 63, bg = tid >> 6;
    float yr0 = 0.f, yi0 = 0.f, yr1 = 0.f, yi1 = 0.f;
    const float* wrp = Wtr + (size_t)mode * 4096 + ih * 2048;
    const float* wip = Wti + (size_t)mode * 4096 + ih * 2048;
#pragma unroll 8
    for (int i = 0; i < 32; ++i) {
        float wr = wrp[i * 64 + o], wi = wip[i * 64 + o];
        float xr = xsr[bg * 32 + i],        xi = xsi[bg * 32 + i];
        yr0 += xr * wr - xi * wi;  yi0 += xr * wi + xi * wr;
        float xr2 = xsr[(bg + 4) * 32 + i], xi2 = xsi[(bg + 4) * 32 + i];
        yr1 += xr2 * wr - xi2 * wi;  yi1 += xr2 * wi + xi2 * wr;
    }
    float* Yr = ih ? YrB : YrA;
    float* Yi = ih ? YiB : YiA;
    const int kxi = mode >> 4, kym = mode & 15;
    const size_t e0 = ((size_t)bg * 64 + o) * 512 + kym * 32 + kxi;
    const size_t e1 = ((size_t)(bg + 4) * 64 + o) * 512 + kym * 32 + kxi;
    Yr[e0] = yr0;  Yi[e0] = yi0;
    Yr[e1] = yr1;  Yi[e1] = yi1;
}

// ---------------- Kernel D (MFMA): Y(A+B) -> Z[b][o][h][ky] ----------------
// grid 1024 = b(8) x og(16) x ri(2) x hs(4). block 256 (4 waves, wave = 16-h frag).
__global__ __launch_bounds__(256) void kd_mfma(const float* __restrict__ YrA,
                                               const float* __restrict__ YiA,
                                               const float* __restrict__ YrB,
                                               const float* __restrict__ YiB,
                                               const unsigned short* __restrict__ tD,
                                               float* __restrict__ Zr,
                                               float* __restrict__ Zi) {
    __shared__ __align__(16) unsigned short at[4096];   // 8 KB: A[64 rows][64 k] swz
    __shared__ __align__(16) float zt[64][68];          // 17.4 KB: [h_local][m] + pad
    const int tid = threadIdx.x;
    const int bid = blockIdx.x;
    const int b  = bid >> 7;
    const int og = (bid >> 3) & 15;
    const int ri = (bid >> 2) & 1;
    const int hs = bid & 3;

    // ---- stage A: row = ol*16+ky, word j=kxi holds (Yr*sc, Yi*sc) bf16 ----
    {
        const int row = tid >> 2, q = tid & 3;
        const int ol = row >> 4, ky = row & 15;
        const float sc = (ky == 0) ? INV256 : 2.f * INV256;
        const size_t yb = ((size_t)(b * 64 + og * 4 + ol)) * 512 + ky * 32 + q * 8;
        f32x4 r0 = *reinterpret_cast<const f32x4*>(YrA + yb)     + *reinterpret_cast<const f32x4*>(YrB + yb);
        f32x4 r1 = *reinterpret_cast<const f32x4*>(YrA + yb + 4) + *reinterpret_cast<const f32x4*>(YrB + yb + 4);
        f32x4 i0 = *reinterpret_cast<const f32x4*>(YiA + yb)     + *reinterpret_cast<const f32x4*>(YiB + yb);
        f32x4 i1 = *reinterpret_cast<const f32x4*>(YiA + yb + 4) + *reinterpret_cast<const f32x4*>(YiB + yb + 4);
        unsigned wbuf[8];
#pragma unroll
        for (int t = 0; t < 4; ++t) {
            wbuf[t]     = bfpack(r0[t] * sc, i0[t] * sc);
            wbuf[4 + t] = bfpack(r1[t] * sc, i1[t] * sc);
        }
        char* base = reinterpret_cast<char*>(at) + row * 128;
        *reinterpret_cast<uint4*>(base + (((2 * q)     ^ (row & 7)) << 4)) = *reinterpret_cast<uint4*>(&wbuf[0]);
        *reinterpret_cast<uint4*>(base + (((2 * q + 1) ^ (row & 7)) << 4)) = *reinterpret_cast<uint4*>(&wbuf[4]);
    }
    __syncthreads();

    const int m = tid & 15, g = (tid >> 4) & 3, wid = tid >> 6;
    const unsigned short* td = tD + ri * 16384;
    const int hg = hs * 64 + wid * 16 + m;

    f32x4 acc[4];
#pragma unroll
    for (int mf = 0; mf < 4; ++mf)
#pragma unroll
        for (int r = 0; r < 4; ++r) acc[mf][r] = 0.f;

#pragma unroll
    for (int ks = 0; ks < 2; ++ks) {
        s16x8 bf = *reinterpret_cast<const s16x8*>(td + hg * 64 + ks * 32 + 8 * g);
#pragma unroll
        for (int mf = 0; mf < 4; ++mf) {
            s16x8 af = *reinterpret_cast<const s16x8*>(
                reinterpret_cast<const char*>(at) + (mf * 16 + m) * 128
                + (((4 * ks + g) ^ (m & 7)) << 4));
            acc[mf] = __builtin_amdgcn_mfma_f32_16x16x32_bf16(af, bf, acc[mf], 0, 0, 0);
        }
    }

#pragma unroll
    for (int mf = 0; mf < 4; ++mf)
#pragma unroll
        for (int r = 0; r < 4; ++r)
            zt[wid * 16 + m][mf * 16 + 4 * g + r] = acc[mf][r];
    __syncthreads();

    float* Zd = ri ? Zi : Zr;
    const int ol = tid >> 6, hloc = (tid >> 2) & 15, kg = tid & 3;
#pragma unroll
    for (int hq = 0; hq < 4; ++hq) {
        f32x4 v = *reinterpret_cast<const f32x4*>(&zt[hq * 16 + hloc][ol * 16 + 4 * kg]);
        size_t off = (((size_t)(b * 64 + og * 4 + ol)) * 256 + hs * 64 + hq * 16 + hloc) * 16 + 4 * kg;
        *reinterpret_cast<f32x4*>(Zd + off) = v;
    }
}

// ---------------- Kernel E (MFMA): out = [cw|Z] @ [x;trig] + bias ----------
// grid 4096 = (b, h, w-half). block 256 (4 waves; wave = 16-o group x 128 w).
__global__ __launch_bounds__(256) void ke_mfma(const float* __restrict__ x,
                                               const float* __restrict__ Zr,
                                               const float* __restrict__ Zi,
                                               const float* __restrict__ cw,
                                               const float* __restrict__ bias,
                                               const unsigned short* __restrict__ ttab,
                                               float* __restrict__ out) {
    __shared__ unsigned int bsx[4096];   // 16 KB: [128 w][32 words], swizzled
    const int tid = threadIdx.x;
    const int b  = blockIdx.x >> 9;
    const int h  = (blockIdx.x >> 1) & 255;
    const int wh = blockIdx.x & 1;
    const int wbase = wh * 128;

    const size_t xbase = ((size_t)b * 64) * 65536 + (size_t)h * 256 + wbase;
    const int wl4 = (tid & 31) * 4;
    const int ipg = tid >> 5;
    float4 va[4], vb[4];
#pragma unroll
    for (int it = 0; it < 4; ++it) {
        int ip = it * 8 + ipg;
        va[it] = *reinterpret_cast<const float4*>(x + xbase + (size_t)(2 * ip) * 65536 + wl4);
        vb[it] = *reinterpret_cast<const float4*>(x + xbase + (size_t)(2 * ip + 1) * 65536 + wl4);
    }

    const int m = tid & 15;
    const int g = (tid >> 4) & 3;
    const int wave = tid >> 6;
    const int o = wave * 16 + m;

    s16x8 a0, a1, az;
    {
        f32x4 p  = *reinterpret_cast<const f32x4*>(cw + o * 64 + 8 * g);
        f32x4 q  = *reinterpret_cast<const f32x4*>(cw + o * 64 + 8 * g + 4);
        f32x4 p2 = *reinterpret_cast<const f32x4*>(cw + o * 64 + 32 + 8 * g);
        f32x4 q2 = *reinterpret_cast<const f32x4*>(cw + o * 64 + 32 + 8 * g + 4);
        size_t zoff = (((size_t)b * 64 + o) * 256 + h) * 16 + 4 * g;
        f32x4 zr = *reinterpret_cast<const f32x4*>(Zr + zoff);
        f32x4 zi = *reinterpret_cast<const f32x4*>(Zi + zoff);
        u32x4 t0 = {bfpack(p[0], p[1]),  bfpack(p[2], p[3]),
                    bfpack(q[0], q[1]),  bfpack(q[2], q[3])};
        u32x4 t1 = {bfpack(p2[0], p2[1]), bfpack(p2[2], p2[3]),
                    bfpack(q2[0], q2[1]), bfpack(q2[2], q2[3])};
        u32x4 tz = {bfpack(zr[0], zi[0]), bfpack(zr[1], zi[1]),
                    bfpack(zr[2], zi[2]), bfpack(zr[3], zi[3])};
        a0 = __builtin_bit_cast(s16x8, t0);
        a1 = __builtin_bit_cast(s16x8, t1);
        az = __builtin_bit_cast(s16x8, tz);
    }
    s16x8 btr[8];
#pragma unroll
    for (int f = 0; f < 8; ++f) {
        int w = wbase + f * 16 + m;
        btr[f] = *reinterpret_cast<const s16x8*>(ttab + w * 32 + 8 * g);
    }
    f32x4 bv = *reinterpret_cast<const f32x4*>(bias + wave * 16 + 4 * g);

#pragma unroll
    for (int it = 0; it < 4; ++it) {
        int ip = it * 8 + ipg;
        const float* pa = reinterpret_cast<const float*>(&va[it]);
        const float* pb = reinterpret_cast<const float*>(&vb[it]);
#pragma unroll
        for (int j = 0; j < 4; ++j) {
            int wl = wl4 + j;
            int c = (wl ^ (wl >> 3)) & 7;
            unsigned pk = bfpack(pa[j], pb[j]);
            bsx[(wl << 5) + ((((ip >> 2) ^ c) << 2) | (ip & 3))] = pk;
        }
    }
    __syncthreads();

    f32x4 acc[8];
#pragma unroll
    for (int f = 0; f < 8; ++f)
#pragma unroll
        for (int r = 0; r < 4; ++r) acc[f][r] = 0.f;

#pragma unroll
    for (int f = 0; f < 8; ++f) {
        int wl = f * 16 + m;
        int c = (wl ^ (wl >> 3)) & 7;
        const char* rb = reinterpret_cast<const char*>(bsx) + (wl << 7);
        s16x8 bx0 = *reinterpret_cast<const s16x8*>(rb + ((g ^ c) << 4));
        s16x8 bx1 = *reinterpret_cast<const s16x8*>(rb + (((4 + g) ^ c) << 4));
        acc[f] = __builtin_amdgcn_mfma_f32_16x16x32_bf16(a0, bx0, acc[f], 0, 0, 0);
        acc[f] = __builtin_amdgcn_mfma_f32_16x16x32_bf16(a1, bx1, acc[f], 0, 0, 0);
        acc[f] = __builtin_amdgcn_mfma_f32_16x16x32_bf16(az, btr[f], acc[f], 0, 0, 0);
    }

    float* ob = out + ((size_t)(b * 64 + wave * 16 + 4 * g)) * 65536 + (size_t)h * 256 + wbase;
#pragma unroll
    for (int f = 0; f < 8; ++f) {
#pragma unroll
        for (int r = 0; r < 4; ++r)
            ob[(size_t)r * 65536 + f * 16 + m] = acc[f][r] + bv[r];
    }
}

extern "C" void kernel_launch(void* const* d_in, const int* in_sizes, int n_in,
                              void* d_out, int out_size, void* d_ws, size_t ws_size,
                              hipStream_t stream) {
    const float* x   = (const float*)d_in[0];
    const float* w1r = (const float*)d_in[1];
    const float* w1i = (const float*)d_in[2];
    const float* w2r = (const float*)d_in[3];
    const float* w2i = (const float*)d_in[4];
    const float* cw  = (const float*)d_in[5];
    const float* cb  = (const float*)d_in[6];
    float* out = (float*)d_out;
    float* ws  = (float*)d_ws;
    unsigned short* tA   = (unsigned short*)(ws + O_TA);
    unsigned short* tB   = (unsigned short*)(ws + O_TB);
    unsigned short* ttab = (unsigned short*)(ws + O_TT);
    unsigned short* tD   = (unsigned short*)(ws + O_TD);

    ktabs<<<320, 256, 0, stream>>>(tA, tB, tD, ttab);
    kw_prep<<<256, 256, 0, stream>>>(w1r, w1i, w2r, w2i, ws + O_WTR, ws + O_WTI);
    kab_fwd<<<512, 256, 0, stream>>>(x, tA, tB, ws + O_XR, ws + O_XI);
    kc_mix<<<1024, 256, 0, stream>>>(ws + O_XR, ws + O_XI, ws + O_WTR, ws + O_WTI,
                                     ws + O_YRA, ws + O_YIA, ws + O_YRB, ws + O_YIB);
    kd_mfma<<<1024, 256, 0, stream>>>(ws + O_YRA, ws + O_YIA, ws + O_YRB, ws + O_YIB,
                                      tD, ws + O_ZR, ws + O_ZI);
    ke_mfma<<<4096, 256, 0, stream>>>(x, ws + O_ZR, ws + O_ZI, cw, cb, ttab, out);
}